// Round 18
// baseline (249.957 us; speedup 1.0000x reference)
//
#include <hip/hip_runtime.h>
#include <hip/hip_bf16.h>
#include <math.h>

#define DEV __device__ __forceinline__

typedef float f32x2 __attribute__((ext_vector_type(2)));

constexpr int B=8, C=64, DIM=256, HID=128, S=64, NH=16, HD=4, LPIX=784;
constexpr int NPIX = B*LPIX;          // 6272
constexpr int CH   = (NPIX+255)/256;  // 25

constexpr size_t OFF_X1O = 0;
constexpr size_t OFF_T1  = OFF_X1O + (size_t)B*C*LPIX;
constexpr size_t OFF_T2  = OFF_T1  + (size_t)B*HID*LPIX;
constexpr size_t OFF_XA  = OFF_T2  + (size_t)B*C*LPIX;
constexpr size_t OFF_BC2 = OFF_XA  + (size_t)B*DIM*LPIX;
constexpr size_t OFF_WGT = OFF_BC2 + (size_t)B*192*LPIX;        // B*S*L (pure softmax probs)
constexpr size_t OFF_H   = OFF_WGT + (size_t)B*S*LPIX;          // 4 * B*C*S
constexpr size_t OFF_HO  = OFF_H   + (size_t)4*B*C*S;
constexpr size_t OFF_QKV = OFF_HO  + (size_t)B*C*S;
constexpr size_t OFF_O   = OFF_QKV + (size_t)3*B*NH*LPIX*HD;    // 4 * B*L*C partials
constexpr size_t OFF_LS  = OFF_O   + (size_t)4*B*LPIX*C;        // 4 * B*NH*L
constexpr size_t OFF_MID = OFF_LS  + (size_t)4*B*NH*LPIX;

DEV float bnorm(float x, const float* p, int c, int nc){
  float g=p[c], bb=p[nc+c], m=p[2*nc+c], v=p[3*nc+c];
  return (x-m)*(g*rsqrtf(v+1e-5f))+bb;
}
DEV int refl(int p){ int k=p-1; if(k<0)k=-k; if(k>27)k=54-k; return k; }

// XCD-pinned decode, 32 groups: blk = (c%8) + 8*g + 256*(c/8), grid 1024.
DEV bool upix_xcd32(int blk, int tid, int& grp, int& b, int& l){
  int c = (blk & 7) + 8*(blk >> 8);
  grp = (blk >> 3) & 31;
  if(c >= CH) return false;
  int gidx = c*256 + tid;
  if(gidx >= NPIX) return false;
  b = gidx / LPIX; l = gidx % LPIX;
  return true;
}

// XCD-pinned decode, 8 groups: blk = (c%8) + 8*g + 64*(c/8), grid 256.
DEV bool upix_xcd8(int blk, int tid, int& grp, int& b, int& l){
  int c = (blk & 7) + 8*(blk >> 6);
  grp = (blk >> 3) & 7;
  if(c >= CH) return false;
  int gidx = c*256 + tid;
  if(gidx >= NPIX) return false;
  b = gidx / LPIX; l = gidx % LPIX;
  return true;
}

// ================= bodies =================
// dw1t: zero-padded 34x34 LDS tile -> straight-line 7x7 conv (no bounds branches)
DEV void body_dw1t(int bc, int tid, float* xs, const float* X, const float* w, const float* bias, const float* bnp, float* out){
  int c = bc & 63, b = bc >> 6;
  const float* xp = X + ((size_t)(b*DIM+c))*LPIX;
  for(int i=tid;i<34*34;i+=256) xs[i]=0.f;
  __syncthreads();
  for(int i=tid;i<LPIX;i+=256){ int y=i/28, x=i%28; xs[(y+3)*34+(x+3)]=xp[i]; }
  __syncthreads();
  const float* wc = w + (size_t)c*49;
  float bs = bias[c];
  for(int i=tid;i<LPIX;i+=256){
    int y=i/28, x=i%28;
    float s = bs;
    #pragma unroll
    for(int ky=0;ky<7;ky++){
      #pragma unroll
      for(int kx=0;kx<7;kx++)
        s += xs[(y+ky)*34 + x+kx]*wc[ky*7+kx];
    }
    out[((size_t)(b*C+c))*LPIX + i] = bnorm(s,bnp,c,C);
  }
}

// branch2: att-conv phase split across two concurrent wave groups —
// waves 0-1 (tid<100) compute h1+v1, waves 2-3 (tid in [128,228)) compute
// h2+v2 into partB; barrier; tid<100 combines + bnorm + sigmoid.
DEV void body_branch2(int bc, int tid, float* smem, const float* X,
                      const float* h1w,const float* v1w,const float* h2w,const float* v2w,
                      const float* bnp, float* xa){
  int c = bc & 63, b = bc >> 6;
  float* xs   = smem;
  float* mp   = smem+LPIX;
  float* xt   = smem+2*LPIX;
  float* attv = smem+2*LPIX+100;
  float* partB= smem+2*LPIX+200;
  const float* xp = X + ((size_t)(b*DIM+64+c))*LPIX;
  for(int i=tid;i<LPIX;i+=256) xs[i]=xp[i];
  __syncthreads();
  for(int i=tid;i<LPIX;i+=256){
    int y=i/28, x=i%28;
    float m=-1e30f;
    for(int dy=-1;dy<=1;dy++){ int iy=y+dy; if(iy<0||iy>=28) continue;
      for(int dx=-1;dx<=1;dx++){ int ix=x+dx; if(ix<0||ix>=28) continue;
        m=fmaxf(m,xs[iy*28+ix]); } }
    mp[i]=m;
  }
  __syncthreads();
  if(tid<100){
    int ii=tid/10, j=tid%10;
    const float fw[4]={0.125f,0.375f,0.375f,0.125f};
    float s=0;
    for(int ky=0;ky<4;ky++){ int rr=refl(3*ii+ky);
      for(int kx=0;kx<4;kx++){ int cc=refl(3*j+kx);
        s += fw[ky]*fw[kx]*mp[rr*28+cc]; } }
    xt[tid]=s;
  }
  __syncthreads();
  if(tid<100){
    // group A: h1 + v1 direct convs
    int r=tid/10, j=tid%10;
    float s=0;
    for(int kh=0;kh<11;kh++){ int a=r+kh-5; if(a<0||a>=10) continue;
      for(int kw=0;kw<3;kw++){ int b2=j+kw-1; if(b2<0||b2>=10) continue;
        s+=xt[a*10+b2]*h1w[(size_t)c*33+kh*3+kw]; } }
    for(int kh=0;kh<3;kh++){ int a=r+kh-1; if(a<0||a>=10) continue;
      for(int kw=0;kw<11;kw++){ int b2=j+kw-5; if(b2<0||b2>=10) continue;
        s+=xt[a*10+b2]*v1w[(size_t)c*33+kh*11+kw]; } }
    attv[tid] = s;   // partial A
  } else if(tid>=128 && tid<228){
    // group B (waves 2-3, concurrent with group A): h2 + v2 transform convs
    int o = tid-128;
    int r=o/10, j=o%10;
    float s=0;
    { int t=20*r+j; int r2=t/19, j2=t%19;
      for(int kh=0;kh<11;kh++){ int a=r2+kh-5; if(a<0||a>=10) continue;
        for(int kw=0;kw<3;kw++){ int b2=j2+kw-1; if(b2<0||b2>=19) continue;
          int i2=19*a+b2; int row=i2/20, col=i2%20;
          if(col<10) s+=xt[row*10+col]*h2w[(size_t)c*33+kh*3+kw]; } } }
    { int t=20*j+r; int p=t%19, q=t/19;
      for(int kh=0;kh<3;kh++){ int a=p+kh-1; if(a<0||a>=19) continue;
        for(int kw=0;kw<11;kw++){ int b2=q+kw-5; if(b2<0||b2>=10) continue;
          int i2=19*b2+a; int row=i2/20, col=i2%20;
          if(col<10) s+=xt[col*10+row]*v2w[(size_t)c*33+kh*11+kw]; } } }
    partB[o] = s;
  }
  __syncthreads();
  if(tid<100){
    float s = bnorm(attv[tid] + partB[tid], bnp, c, C);
    attv[tid] = 1.f/(1.f+__expf(-s));
  }
  __syncthreads();
  float* dst = xa + ((size_t)(b*DIM+64+c))*LPIX;
  for(int i=tid;i<LPIX;i+=256){
    int y=i/28, x=i%28;
    float a = attv[((y*10)/28)*10 + (x*10)/28];
    dst[i] = xs[i]*a;
  }
}

// qkv: XCD-pinned; packed f32x2 math (pairs of input channels). grid 192.
DEV void body_qkv(int blk, int tid, const float* X, const float* w, float* qkvb){
  int c = (blk & 7) + 8*(blk/96);
  int og = (blk >> 3) % 12;
  if(c >= 13) return;
  int p0 = c*512 + tid;
  if(p0 >= NPIX) return;
  int o0 = og*16;
  int b0 = p0/LPIX, l0 = p0%LPIX;
  int p1 = p0 + 256;
  bool has1 = p1 < NPIX;
  int b1 = has1 ? p1/LPIX : b0, l1 = has1 ? p1%LPIX : l0;
  const float* xp0 = X + ((size_t)(b0*DIM+192))*LPIX + l0;
  const float* xp1 = X + ((size_t)(b1*DIM+192))*LPIX + l1;
  f32x2 s0[16], s1[16];
  #pragma unroll
  for(int t=0;t<16;t++){ s0[t]=0.f; s1[t]=0.f; }
  for(int cc=0;cc<C;cc+=4){
    f32x2 a01={xp0[(size_t)cc*LPIX],     xp0[(size_t)(cc+1)*LPIX]};
    f32x2 a23={xp0[(size_t)(cc+2)*LPIX], xp0[(size_t)(cc+3)*LPIX]};
    f32x2 e01={xp1[(size_t)cc*LPIX],     xp1[(size_t)(cc+1)*LPIX]};
    f32x2 e23={xp1[(size_t)(cc+2)*LPIX], xp1[(size_t)(cc+3)*LPIX]};
    #pragma unroll
    for(int t=0;t<16;t++){
      const float* wr = w + (size_t)(o0+t)*C + cc;
      f32x2 w01 = *(const f32x2*)(wr);
      f32x2 w23 = *(const f32x2*)(wr+2);
      s0[t] += w01*a01 + w23*a23;
      s1[t] += w01*e01 + w23*e23;
    }
  }
  int which=o0>>6, head0=(o0&63)>>2;
  #pragma unroll
  for(int t4=0;t4<4;t4++){
    float4* dst = (float4*)(qkvb + (size_t)which*B*NH*LPIX*HD + ((size_t)((b0*NH+head0+t4)*LPIX+l0))*HD);
    *dst = make_float4(s0[4*t4].x+s0[4*t4].y, s0[4*t4+1].x+s0[4*t4+1].y,
                       s0[4*t4+2].x+s0[4*t4+2].y, s0[4*t4+3].x+s0[4*t4+3].y);
  }
  if(has1){
    #pragma unroll
    for(int t4=0;t4<4;t4++){
      float4* dst = (float4*)(qkvb + (size_t)which*B*NH*LPIX*HD + ((size_t)((b1*NH+head0+t4)*LPIX+l1))*HD);
      *dst = make_float4(s1[4*t4].x+s1[4*t4].y, s1[4*t4+1].x+s1[4*t4+1].y,
                         s1[4*t4+2].x+s1[4*t4+2].y, s1[4*t4+3].x+s1[4*t4+3].y);
    }
  }
}

// bcdtssd: XCD-pinned on batch (b = blk&7); stage-1 packed f32x2. grid 384.
DEV void body_bcdtssd(int blk, int tid, float* smem, const float* X, const float* w, const float* dww,
                      float* bc2, float* wgt){
  int b = blk & 7, og = blk >> 3; int o0=og*4;
  float* bc1s = smem;            // 4*784
  const float* xp = X + ((size_t)(b*DIM+128))*LPIX;
  {
    int l0=tid, l1=tid+256, l2=tid+512;
    f32x2 acc0[4], acc1[4], acc2[4];
    #pragma unroll
    for(int t=0;t<4;t++){ acc0[t]=0.f; acc1[t]=0.f; acc2[t]=0.f; }
    for(int c=0;c<C;c+=4){
      f32x2 x0a={xp[(size_t)c*LPIX+l0],     xp[(size_t)(c+1)*LPIX+l0]};
      f32x2 x0b={xp[(size_t)(c+2)*LPIX+l0], xp[(size_t)(c+3)*LPIX+l0]};
      f32x2 x1a={xp[(size_t)c*LPIX+l1],     xp[(size_t)(c+1)*LPIX+l1]};
      f32x2 x1b={xp[(size_t)(c+2)*LPIX+l1], xp[(size_t)(c+3)*LPIX+l1]};
      f32x2 x2a={xp[(size_t)c*LPIX+l2],     xp[(size_t)(c+1)*LPIX+l2]};
      f32x2 x2b={xp[(size_t)(c+2)*LPIX+l2], xp[(size_t)(c+3)*LPIX+l2]};
      #pragma unroll
      for(int t=0;t<4;t++){
        const float* wr = w + (size_t)(o0+t)*C + c;
        f32x2 wa = *(const f32x2*)(wr);
        f32x2 wb = *(const f32x2*)(wr+2);
        acc0[t] += wa*x0a + wb*x0b;
        acc1[t] += wa*x1a + wb*x1b;
        acc2[t] += wa*x2a + wb*x2b;
      }
    }
    #pragma unroll
    for(int t=0;t<4;t++){
      bc1s[t*LPIX+l0]=acc0[t].x+acc0[t].y;
      bc1s[t*LPIX+l1]=acc1[t].x+acc1[t].y;
      bc1s[t*LPIX+l2]=acc2[t].x+acc2[t].y;
    }
    if(tid<16){
      int l=768+tid;
      f32x2 a0=0.f,a1=0.f,a2=0.f,a3=0.f;
      for(int c=0;c<C;c+=2){
        f32x2 xv={xp[(size_t)c*LPIX+l], xp[(size_t)(c+1)*LPIX+l]};
        a0 += (*(const f32x2*)(w + (size_t)(o0+0)*C + c))*xv;
        a1 += (*(const f32x2*)(w + (size_t)(o0+1)*C + c))*xv;
        a2 += (*(const f32x2*)(w + (size_t)(o0+2)*C + c))*xv;
        a3 += (*(const f32x2*)(w + (size_t)(o0+3)*C + c))*xv;
      }
      bc1s[0*LPIX+l]=a0.x+a0.y; bc1s[1*LPIX+l]=a1.x+a1.y;
      bc1s[2*LPIX+l]=a2.x+a2.y; bc1s[3*LPIX+l]=a3.x+a3.y;
    }
  }
  __syncthreads();
  if(og < 32){
    for(int i=tid;i<4*LPIX;i+=256){
      int oo=i/LPIX, l=i%LPIX; int y=l/28, x=l%28;
      const float* p = bc1s + oo*LPIX;
      const float* wk = dww + (size_t)(o0+oo)*9;
      float s=0;
      for(int ky=0;ky<3;ky++){ int iy=y+ky-1; if(iy<0||iy>=28) continue;
        for(int kx=0;kx<3;kx++){ int ix=x+kx-1; if(ix<0||ix>=28) continue;
          s += p[iy*28+ix]*wk[ky*3+kx]; } }
      bc2[((size_t)(b*192+o0+oo))*LPIX + l] = s;
    }
  } else {
    float cv[13];
    #pragma unroll
    for(int k=0;k<13;k++){
      int i = tid + k*256;
      if(i < 4*LPIX){
        int oo=i/LPIX, l=i%LPIX; int y=l/28, x=l%28;
        const float* p = bc1s + oo*LPIX;
        const float* wk = dww + (size_t)(o0+oo)*9;
        float s=0;
        for(int ky=0;ky<3;ky++){ int iy=y+ky-1; if(iy<0||iy>=28) continue;
          for(int kx=0;kx<3;kx++){ int ix=x+kx-1; if(ix<0||ix>=28) continue;
            s += p[iy*28+ix]*wk[ky*3+kx]; } }
        cv[k]=s;
      }
    }
    __syncthreads();
    #pragma unroll
    for(int k=0;k<13;k++){ int i=tid+k*256; if(i<4*LPIX) bc1s[i]=cv[k]; }
    __syncthreads();
    int wv = tid>>6, lane = tid&63;
    float* row = bc1s + wv*LPIX;
    float mx = -1e30f;
    for(int l=lane;l<LPIX;l+=64) mx = fmaxf(mx, row[l]);
    for(int off=32;off;off>>=1) mx = fmaxf(mx, __shfl_xor(mx,off));
    float sum=0;
    for(int l=lane;l<LPIX;l+=64){ float e=__expf(row[l]-mx); row[l]=e; sum+=e; }
    for(int off=32;off;off>>=1) sum += __shfl_xor(sum,off);
    float inv = 1.f/sum;
    int s_ = o0-128+wv;
    float* wp = wgt + ((size_t)(b*S+s_))*LPIX;
    for(int l=lane;l<LPIX;l+=64) wp[l] = row[l]*inv;
  }
}

// attn: packed-pair form (r14, proven). K/V pair-interleaved in LDS.
DEV void body_attn(int blk, int tid, float* kp, float* vp, const float* qkvb,
                   float* ob, float* lsb){
  int bh = blk >> 2, ms = blk & 3;
  int b = bh>>4, h = bh&15;
  const float4* q4 = (const float4*)(qkvb + (size_t)bh*LPIX*HD);
  const float4* k4 = (const float4*)(qkvb + (size_t)(B*NH + bh)*LPIX*HD) + ms*196;
  const float4* v4 = (const float4*)(qkvb + (size_t)(2*B*NH + bh)*LPIX*HD) + ms*196;
  for(int i=tid;i<196;i+=256){
    float4 kv=k4[i]; float4 vv=v4[i];
    int m=i>>1, e=i&1;
    float* kd = kp + m*8 + e;
    kd[0]=kv.x; kd[2]=kv.y; kd[4]=kv.z; kd[6]=kv.w;
    float* vd = vp + m*8 + e;
    vd[0]=vv.x; vd[2]=vv.y; vd[4]=vv.z; vd[6]=vv.w;
  }
  __syncthreads();
  const float SC = 0.5f*1.44269504f;
  float* obp = ob + (size_t)ms*B*LPIX*C;
  float* lsq = lsb + (size_t)ms*B*NH*LPIX + (size_t)bh*LPIX;

  float4 q[3];
  #pragma unroll
  for(int j=0;j<3;j++){
    float4 t = q4[tid + 256*j];
    q[j] = make_float4(t.x*SC, t.y*SC, t.z*SC, t.w*SC);
  }
  f32x2 l[3], ax[3], ay[3], az[3], aw[3];
  #pragma unroll
  for(int j=0;j<3;j++){ l[j]=0.f; ax[j]=0.f; ay[j]=0.f; az[j]=0.f; aw[j]=0.f; }
  for(int m=0;m<98;m++){
    float4 kxy = *(const float4*)(kp + m*8);
    float4 kzw = *(const float4*)(kp + m*8 + 4);
    float4 vxy = *(const float4*)(vp + m*8);
    float4 vzw = *(const float4*)(vp + m*8 + 4);
    f32x2 kx={kxy.x,kxy.y}, ky={kxy.z,kxy.w}, kz={kzw.x,kzw.y}, kw={kzw.z,kzw.w};
    f32x2 vx={vxy.x,vxy.y}, vy={vxy.z,vxy.w}, vz={vzw.x,vzw.y}, vw={vzw.z,vzw.w};
    #pragma unroll
    for(int j=0;j<3;j++){
      f32x2 sc = kx*q[j].x + ky*q[j].y + kz*q[j].z + kw*q[j].w;
      f32x2 p = { __builtin_amdgcn_exp2f(sc.x), __builtin_amdgcn_exp2f(sc.y) };
      l[j] += p;
      ax[j] += p*vx; ay[j] += p*vy; az[j] += p*vz; aw[j] += p*vw;
    }
  }
  #pragma unroll
  for(int j=0;j<3;j++){
    int r = tid + 256*j;
    *(float4*)(obp + ((size_t)(b*LPIX+r))*C + h*4) =
        make_float4(ax[j].x+ax[j].y, ay[j].x+ay[j].y, az[j].x+az[j].y, aw[j].x+aw[j].y);
    lsq[r] = l[j].x+l[j].y;
  }
  if(tid < 16){
    int r = 768 + tid;
    float4 t = q4[r];
    float4 qq = make_float4(t.x*SC,t.y*SC,t.z*SC,t.w*SC);
    f32x2 ls=0.f, bx=0.f, by=0.f, bz=0.f, bw=0.f;
    for(int m=0;m<98;m++){
      float4 kxy = *(const float4*)(kp + m*8);
      float4 kzw = *(const float4*)(kp + m*8 + 4);
      float4 vxy = *(const float4*)(vp + m*8);
      float4 vzw = *(const float4*)(vp + m*8 + 4);
      f32x2 kx={kxy.x,kxy.y}, ky={kxy.z,kxy.w}, kz={kzw.x,kzw.y}, kw={kzw.z,kzw.w};
      f32x2 vx={vxy.x,vxy.y}, vy={vxy.z,vxy.w}, vz={vzw.x,vzw.y}, vw={vzw.z,vzw.w};
      f32x2 sc = kx*qq.x + ky*qq.y + kz*qq.z + kw*qq.w;
      f32x2 p = { __builtin_amdgcn_exp2f(sc.x), __builtin_amdgcn_exp2f(sc.y) };
      ls += p; bx += p*vx; by += p*vy; bz += p*vz; bw += p*vw;
    }
    *(float4*)(obp + ((size_t)(b*LPIX+r))*C + h*4) =
        make_float4(bx.x+bx.y, by.x+by.y, bz.x+bz.y, bw.x+bw.y);
    lsq[r] = ls.x+ls.y;
  }
}

// star: XCD-pinned; packed f32x2 (4 pair-chunks per 8-wide step). grid 1024.
DEV void body_star(int blk, int tid, const float* x1o, const float* f1w,const float* f1b,const float* f2w,const float* f2b,float* t1){
  int jg, b, l; if(!upix_xcd32(blk, tid, jg, b, l)) return;
  int j0=jg*4;
  const float* xp = x1o + (size_t)b*C*LPIX + l;
  f32x2 a[4], g[4];
  #pragma unroll
  for(int t=0;t<4;t++){ a[t]=0.f; g[t]=0.f; }
  for(int c=0;c<C;c+=8){
    f32x2 xA={xp[(size_t)c*LPIX],     xp[(size_t)(c+1)*LPIX]};
    f32x2 xB={xp[(size_t)(c+2)*LPIX], xp[(size_t)(c+3)*LPIX]};
    f32x2 xC={xp[(size_t)(c+4)*LPIX], xp[(size_t)(c+5)*LPIX]};
    f32x2 xD={xp[(size_t)(c+6)*LPIX], xp[(size_t)(c+7)*LPIX]};
    #pragma unroll
    for(int t=0;t<4;t++){
      const float* f1r = f1w + (size_t)(j0+t)*C + c;
      const float* f2r = f2w + (size_t)(j0+t)*C + c;
      a[t] += (*(const f32x2*)(f1r))*xA + (*(const f32x2*)(f1r+2))*xB
            + (*(const f32x2*)(f1r+4))*xC + (*(const f32x2*)(f1r+6))*xD;
      g[t] += (*(const f32x2*)(f2r))*xA + (*(const f32x2*)(f2r+2))*xB
            + (*(const f32x2*)(f2r+4))*xC + (*(const f32x2*)(f2r+6))*xD;
    }
  }
  for(int t=0;t<4;t++){
    float av = fminf(fmaxf(a[t].x+a[t].y+f1b[j0+t],0.f),6.f);
    float gv = g[t].x+g[t].y+f2b[j0+t];
    t1[((size_t)(b*HID+j0+t))*LPIX + l] = av*gv;
  }
}

// gproj: XCD-pinned; packed f32x2. grid 256.
DEV void body_gproj(int blk, int tid, const float* t1, const float* gw,const float* gb,const float* bnp,float* t2){
  int cg, b, l; if(!upix_xcd8(blk, tid, cg, b, l)) return;
  int c0=cg*8;
  const float* tp = t1 + (size_t)b*HID*LPIX + l;
  f32x2 s[8];
  #pragma unroll
  for(int t=0;t<8;t++) s[t]=0.f;
  for(int j=0;j<HID;j+=4){
    f32x2 xA={tp[(size_t)j*LPIX],     tp[(size_t)(j+1)*LPIX]};
    f32x2 xB={tp[(size_t)(j+2)*LPIX], tp[(size_t)(j+3)*LPIX]};
    #pragma unroll
    for(int t=0;t<8;t++){
      const float* wr = gw + (size_t)(c0+t)*HID + j;
      s[t] += (*(const f32x2*)(wr))*xA + (*(const f32x2*)(wr+2))*xB;
    }
  }
  #pragma unroll
  for(int t=0;t<8;t++)
    t2[((size_t)(b*C+c0+t))*LPIX + l]=bnorm(s[t].x+s[t].y+gb[c0+t],bnp,c0+t,C);
}

// x4: XCD-pinned; packed f32x2 on the proj inner. grid 256.
DEV void body_x4(int blk, int tid, const float* X, const float* ob, const float* lsb,
                 const float* projw, const float* bnp, float* xa){
  int cg, b, l; if(!upix_xcd8(blk, tid, cg, b, l)) return;
  int c0=cg*8;
  const float* p0 = ob + ((size_t)(b*LPIX+l))*C;
  const float* p1 = p0 + (size_t)B*LPIX*C;
  const float* p2 = p1 + (size_t)B*LPIX*C;
  const float* p3 = p2 + (size_t)B*LPIX*C;
  f32x2 s[8];
  #pragma unroll
  for(int t=0;t<8;t++) s[t]=0.f;
  for(int h=0;h<NH;h++){
    size_t li = ((size_t)(b*NH+h))*LPIX + l;
    float lsum = lsb[li] + lsb[(size_t)B*NH*LPIX+li] + lsb[(size_t)2*B*NH*LPIX+li] + lsb[(size_t)3*B*NH*LPIX+li];
    float iv = 1.f/lsum;
    float4 q0=*(const float4*)(p0+h*4), q1=*(const float4*)(p1+h*4),
           q2=*(const float4*)(p2+h*4), q3=*(const float4*)(p3+h*4);
    f32x2 ovA = { (q0.x+q1.x+q2.x+q3.x)*iv, (q0.y+q1.y+q2.y+q3.y)*iv };
    f32x2 ovB = { (q0.z+q1.z+q2.z+q3.z)*iv, (q0.w+q1.w+q2.w+q3.w)*iv };
    const float* pw = projw + h*4;
    #pragma unroll
    for(int t=0;t<8;t++){
      const float* pr = pw + (size_t)(c0+t)*C;
      s[t] += (*(const f32x2*)(pr))*ovA + (*(const f32x2*)(pr+2))*ovB;
    }
  }
  #pragma unroll
  for(int t=0;t<8;t++){
    float v = s[t].x+s[t].y + X[((size_t)(b*DIM+192+c0+t))*LPIX + l];
    xa[((size_t)(b*DIM+192+c0+t))*LPIX + l] = bnorm(v,bnp,c0+t,C);
  }
}

// h: XCD-pinned on batch (b = blk&7); l-tile split into 2x98 halves. grid 512.
DEV void body_h(int blk, int tid, float* smem, const float* X, const float* wgt, const float* bc2, float* hq){
  int b = blk & 7, sub = blk >> 3;
  int tile = sub >> 2, qq = sub & 3;
  int ct = (tile>>2)*16, st = (tile&3)*16;
  float (*Xs)[99] = (float(*)[99])smem;
  float (*Ws)[99] = (float(*)[99])(smem + 16*99);
  int tc = tid>>4, ts = tid&15;
  float acc=0;
  #pragma unroll
  for(int half=0;half<2;half++){
    int lb = qq*196 + half*98;
    for(int i=tid;i<16*98;i+=256){
      int r=i/98, col=i%98;
      Xs[r][col] = X[((size_t)(b*DIM+128+ct+r))*LPIX + lb + col];
      Ws[r][col] = wgt[((size_t)(b*S+st+r))*LPIX + lb + col]
                 * bc2[((size_t)(b*192+st+r))*LPIX + lb + col];
    }
    __syncthreads();
    #pragma unroll 7
    for(int l=0;l<98;l++) acc += Xs[tc][l]*Ws[ts][l];
    __syncthreads();
  }
  hq[(size_t)qq*B*C*S + ((size_t)(b*C+ct+tc))*S + st+ts] = acc;
}

// dw2t: zero-padded 34x34 LDS tile, straight-line 7x7 conv
DEV void body_dw2t(int bc, int tid, float* xs, const float* t2, const float* w, const float* bias, float* xa){
  int c = bc & 63, b = bc >> 6;
  const float* tp = t2 + ((size_t)(b*C+c))*LPIX;
  for(int i=tid;i<34*34;i+=256) xs[i]=0.f;
  __syncthreads();
  for(int i=tid;i<LPIX;i+=256){ int y=i/28, x=i%28; xs[(y+3)*34+(x+3)]=tp[i]; }
  __syncthreads();
  const float* wc = w + (size_t)c*49;
  float bs = bias[c];
  for(int i=tid;i<LPIX;i+=256){
    int y=i/28, x=i%28;
    float s = bs;
    #pragma unroll
    for(int ky=0;ky<7;ky++){
      #pragma unroll
      for(int kx=0;kx<7;kx++)
        s += xs[(y+ky)*34 + x+kx]*wc[ky*7+kx];
    }
    xa[((size_t)(b*DIM+c))*LPIX + i] = s;
  }
}

DEV void body_mixho(int blk, int tid, float* smem, const float* hq, const float* hzw,
                    const float* Dp, const float* outw, float* ho){
  int b = blk >> 3, st = (blk & 7) * 8;
  float (*hs2)[8] = (float(*)[8])smem;
  float (*g1s)[8] = (float(*)[8])(smem + C*8);
  for(int i=tid;i<C*8;i+=256){
    int k=i>>3, si=i&7;
    size_t off = ((size_t)(b*C+k))*S + st + si;
    hs2[k][si] = hq[off] + hq[(size_t)B*C*S+off] + hq[(size_t)2*B*C*S+off] + hq[(size_t)3*B*C*S+off];
  }
  __syncthreads();
  float D = Dp[0];
  for(int i=tid;i<C*8;i+=256){
    int c=i>>3, si=i&7;
    float hv=0, zv=0;
    for(int k=0;k<C;k++){ float x=hs2[k][si]; hv+=hzw[(size_t)c*C+k]*x; zv+=hzw[(size_t)(C+c)*C+k]*x; }
    float sil = zv/(1.f+__expf(-zv));
    g1s[c][si]=hv*sil+hv*D;
  }
  __syncthreads();
  for(int i=tid;i<C*8;i+=256){
    int c=i>>3, si=i&7;
    float acc=0;
    for(int k=0;k<C;k++) acc+=outw[(size_t)c*C+k]*g1s[k][si];
    ho[((size_t)(b*C+c))*S + st + si]=acc;
  }
}

// x3: XCD-pinned; packed f32x2 (hp pairs are contiguous). grid 256.
DEV void body_x3(int blk, int tid, const float* ho, const float* bc2, float* xa){
  int cg, b, l; if(!upix_xcd8(blk, tid, cg, b, l)) return;
  int c0=cg*8;
  const float* hp = ho + (size_t)(b*C+c0)*S;
  const float* cm = bc2 + ((size_t)(b*192+64))*LPIX + l;
  f32x2 s[8];
  #pragma unroll
  for(int t=0;t<8;t++) s[t]=0.f;
  for(int s_=0;s_<S;s_+=2){
    f32x2 cv = { cm[(size_t)s_*LPIX], cm[(size_t)(s_+1)*LPIX] };
    #pragma unroll
    for(int t=0;t<8;t++)
      s[t] += (*(const f32x2*)(hp + (size_t)t*S + s_))*cv;
  }
  #pragma unroll
  for(int t=0;t<8;t++)
    xa[((size_t)(b*DIM+128+c0+t))*LPIX + l] = s[t].x+s[t].y;
}

// ================= stage kernels =================
// S1: [0,384)=bcdtssd  [384,896)=branch2  [896,1088)=qkv  [1088,1600)=dw1t
__global__ void k_s1(const float* X,
                     const float* bcdt_w, const float* ssd_dw, float* bc2, float* wgt,
                     const float* h1w,const float* v1w,const float* h2w,const float* v2w,const float* bn_mra,
                     const float* qkv_w, float* qkvb,
                     const float* dw1_w,const float* dw1_b,const float* bn_dw1,
                     float* xa, float* x1o){
  __shared__ float smem[4*LPIX];
  int blk = blockIdx.x, tid = threadIdx.x;
  if(blk < 384)            body_bcdtssd(blk, tid, smem, X, bcdt_w, ssd_dw, bc2, wgt);
  else if(blk < 896)       body_branch2(blk-384, tid, smem, X, h1w,v1w,h2w,v2w, bn_mra, xa);
  else if(blk < 1088)      body_qkv(blk-896, tid, X, qkv_w, qkvb);
  else                     body_dw1t(blk-1088, tid, smem, X, dw1_w, dw1_b, bn_dw1, x1o);
}

// S2: [0,512)=attn  [512,1536)=star  [1536,2048)=h   (LDS 3168 floats = 12.7KB)
__global__ void k_s2(const float* qkvb, float* ob, float* lsb,
                     const float* x1o, const float* f1w,const float* f1b,const float* f2w,const float* f2b, float* t1,
                     const float* X, const float* wgt, const float* bc2, float* hq){
  __shared__ float smem[3168];
  int blk = blockIdx.x, tid = threadIdx.x;
  if(blk < 512)            body_attn(blk, tid, smem, smem+784, qkvb, ob, lsb);
  else if(blk < 1536)      body_star(blk-512, tid, x1o, f1w,f1b,f2w,f2b, t1);
  else                     body_h(blk-1536, tid, smem, X, wgt, bc2, hq);
}

// S3: [0,64)=mixho  [64,320)=gproj  [320,576)=x4
__global__ void k_s3(const float* t1, const float* gw,const float* gb,const float* bn_g, float* t2,
                     const float* X, const float* ob, const float* lsb,
                     const float* projw, const float* bn_n4, float* xa,
                     const float* hq, const float* hzw, const float* Dp, const float* outw, float* ho){
  __shared__ float smem[2*C*8];
  int blk = blockIdx.x, tid = threadIdx.x;
  if(blk < 64)        body_mixho(blk, tid, smem, hq, hzw, Dp, outw, ho);
  else if(blk < 320)  body_gproj(blk-64, tid, t1, gw, gb, bn_g, t2);
  else                body_x4(blk-320, tid, X, ob, lsb, projw, bn_n4, xa);
}

// S4: [0,512)=dw2t  [512,768)=x3
__global__ void k_s4(const float* t2, const float* dw2_w, const float* dw2_b, float* xa,
                     const float* ho, const float* bc2){
  __shared__ float smem[34*34];
  int blk = blockIdx.x, tid = threadIdx.x;
  if(blk < 512) body_dw2t(blk, tid, smem, t2, dw2_w, dw2_b, xa);
  else          body_x3(blk-512, tid, ho, bc2, xa);
}

// mid: XCD-pinned; packed f32x2. grid 1024.
__global__ void k_mid(const float* xa, const float* m1w, const float* bnp, float* mid){
  int jg, b, l; if(!upix_xcd32(blockIdx.x, threadIdx.x, jg, b, l)) return;
  int j0=jg*4;
  const float* xp = xa + (size_t)b*DIM*LPIX + l;
  f32x2 s[4];
  #pragma unroll
  for(int t=0;t<4;t++) s[t]=0.f;
  for(int c=0;c<DIM;c+=8){
    f32x2 xA={xp[(size_t)c*LPIX],     xp[(size_t)(c+1)*LPIX]};
    f32x2 xB={xp[(size_t)(c+2)*LPIX], xp[(size_t)(c+3)*LPIX]};
    f32x2 xC={xp[(size_t)(c+4)*LPIX], xp[(size_t)(c+5)*LPIX]};
    f32x2 xD={xp[(size_t)(c+6)*LPIX], xp[(size_t)(c+7)*LPIX]};
    #pragma unroll
    for(int t=0;t<4;t++){
      const float* wr = m1w + (size_t)(j0+t)*DIM + c;
      s[t] += (*(const f32x2*)(wr))*xA + (*(const f32x2*)(wr+2))*xB
            + (*(const f32x2*)(wr+4))*xC + (*(const f32x2*)(wr+6))*xD;
    }
  }
  for(int t=0;t<4;t++)
    mid[((size_t)(b*HID+j0+t))*LPIX + l] = fmaxf(bnorm(s[t].x+s[t].y,bnp,j0+t,HID),0.f);
}

// out: XCD-pinned; packed f32x2. grid 1024.
__global__ void k_out(const float* X, const float* mid, const float* m2w, const float* bnp, float* out){
  int cg, b, l; if(!upix_xcd32(blockIdx.x, threadIdx.x, cg, b, l)) return;
  int c0=cg*8;
  const float* mp_ = mid + (size_t)b*HID*LPIX + l;
  f32x2 s[8];
  #pragma unroll
  for(int t=0;t<8;t++) s[t]=0.f;
  for(int j=0;j<HID;j+=8){
    f32x2 mA={mp_[(size_t)j*LPIX],     mp_[(size_t)(j+1)*LPIX]};
    f32x2 mB={mp_[(size_t)(j+2)*LPIX], mp_[(size_t)(j+3)*LPIX]};
    f32x2 mC={mp_[(size_t)(j+4)*LPIX], mp_[(size_t)(j+5)*LPIX]};
    f32x2 mD={mp_[(size_t)(j+6)*LPIX], mp_[(size_t)(j+7)*LPIX]};
    #pragma unroll
    for(int t=0;t<8;t++){
      const float* wr = m2w + (size_t)(c0+t)*HID + j;
      s[t] += (*(const f32x2*)(wr))*mA + (*(const f32x2*)(wr+2))*mB
            + (*(const f32x2*)(wr+4))*mC + (*(const f32x2*)(wr+6))*mD;
    }
  }
  for(int t=0;t<8;t++){
    size_t oi = ((size_t)(b*DIM+c0+t))*LPIX + l;
    out[oi] = bnorm(s[t].x+s[t].y,bnp,c0+t,DIM) + X[oi];
  }
}

extern "C" void kernel_launch(void* const* d_in, const int* in_sizes, int n_in,
                              void* d_out, int out_size, void* d_ws, size_t ws_size,
                              hipStream_t stream) {
  const float* X      = (const float*)d_in[0];
  const float* dw1_w  = (const float*)d_in[1];
  const float* dw1_b  = (const float*)d_in[2];
  const float* bn_dw1 = (const float*)d_in[3];
  const float* f1_w   = (const float*)d_in[4];
  const float* f1_b   = (const float*)d_in[5];
  const float* f2_w   = (const float*)d_in[6];
  const float* f2_b   = (const float*)d_in[7];
  const float* g_w    = (const float*)d_in[8];
  const float* g_b    = (const float*)d_in[9];
  const float* bn_g   = (const float*)d_in[10];
  const float* dw2_w  = (const float*)d_in[11];
  const float* dw2_b  = (const float*)d_in[12];
  const float* hatt1w = (const float*)d_in[13];
  const float* vatt1w = (const float*)d_in[14];
  const float* hatt2w = (const float*)d_in[15];
  const float* vatt2w = (const float*)d_in[16];
  const float* bn_mra = (const float*)d_in[17];
  const float* bcdt_w = (const float*)d_in[18];
  const float* ssd_dw = (const float*)d_in[19];
  const float* hz_w   = (const float*)d_in[20];
  const float* out_w  = (const float*)d_in[21];
  const float* D_p    = (const float*)d_in[23];
  const float* qkv_w  = (const float*)d_in[24];
  const float* proj_w = (const float*)d_in[25];
  const float* bn_n4  = (const float*)d_in[26];
  const float* mlp1_w = (const float*)d_in[27];
  const float* bn_mlp = (const float*)d_in[28];
  const float* mlp2_w = (const float*)d_in[29];
  const float* bn_n1  = (const float*)d_in[30];

  float* ws   = (float*)d_ws;
  float* x1o  = ws+OFF_X1O;  float* t1  = ws+OFF_T1;  float* t2  = ws+OFF_T2;
  float* xa   = ws+OFF_XA;   float* bc2 = ws+OFF_BC2; float* wgt = ws+OFF_WGT;
  float* hq   = ws+OFF_H;    float* ho  = ws+OFF_HO;  float* qkvb= ws+OFF_QKV;
  float* ob   = ws+OFF_O;    float* lsb = ws+OFF_LS;  float* mid = ws+OFF_MID;

  dim3 blk(256);

  k_s1 <<<dim3(1600),blk,0,stream>>>(X, bcdt_w, ssd_dw, bc2, wgt,
                                     hatt1w,vatt1w,hatt2w,vatt2w,bn_mra,
                                     qkv_w, qkvb, dw1_w,dw1_b,bn_dw1, xa, x1o);
  k_s2 <<<dim3(2048),blk,0,stream>>>(qkvb, ob, lsb,
                                     x1o, f1_w,f1_b,f2_w,f2_b, t1,
                                     X, wgt, bc2, hq);
  k_s3 <<<dim3(576),blk,0,stream>>>(t1, g_w,g_b,bn_g, t2,
                                     X, ob, lsb, proj_w, bn_n4, xa,
                                     hq, hz_w, D_p, out_w, ho);
  k_s4 <<<dim3(768),blk,0,stream>>>(t2, dw2_w, dw2_b, xa, ho, bc2);
  k_mid<<<dim3(1024),blk,0,stream>>>(xa,mlp1_w,bn_mlp,mid);
  k_out<<<dim3(1024),blk,0,stream>>>(X,mid,mlp2_w,bn_n1,(float*)d_out);
}

// Round 19
// 246.968 us; speedup vs baseline: 1.0121x; 1.0121x over previous
//
#include <hip/hip_runtime.h>
#include <hip/hip_bf16.h>
#include <math.h>

#define DEV __device__ __forceinline__

typedef float f32x2 __attribute__((ext_vector_type(2)));

constexpr int B=8, C=64, DIM=256, HID=128, S=64, NH=16, HD=4, LPIX=784;
constexpr int NPIX = B*LPIX;          // 6272
constexpr int CH   = (NPIX+255)/256;  // 25

constexpr size_t OFF_X1O = 0;
constexpr size_t OFF_T1  = OFF_X1O + (size_t)B*C*LPIX;
constexpr size_t OFF_T2  = OFF_T1  + (size_t)B*HID*LPIX;
constexpr size_t OFF_XA  = OFF_T2  + (size_t)B*C*LPIX;
constexpr size_t OFF_BC2 = OFF_XA  + (size_t)B*DIM*LPIX;
constexpr size_t OFF_WGT = OFF_BC2 + (size_t)B*192*LPIX;        // B*S*L (pure softmax probs)
constexpr size_t OFF_H   = OFF_WGT + (size_t)B*S*LPIX;          // 4 * B*C*S
constexpr size_t OFF_HO  = OFF_H   + (size_t)4*B*C*S;
constexpr size_t OFF_QKV = OFF_HO  + (size_t)B*C*S;
constexpr size_t OFF_O   = OFF_QKV + (size_t)3*B*NH*LPIX*HD;    // 4 * B*L*C partials
constexpr size_t OFF_LS  = OFF_O   + (size_t)4*B*LPIX*C;        // 4 * B*NH*L
constexpr size_t OFF_MID = OFF_LS  + (size_t)4*B*NH*LPIX;

DEV float bnorm(float x, const float* p, int c, int nc){
  float g=p[c], bb=p[nc+c], m=p[2*nc+c], v=p[3*nc+c];
  return (x-m)*(g*rsqrtf(v+1e-5f))+bb;
}
DEV int refl(int p){ int k=p-1; if(k<0)k=-k; if(k>27)k=54-k; return k; }

// XCD-pinned decode, 32 groups: blk = (c%8) + 8*g + 256*(c/8), grid 1024.
DEV bool upix_xcd32(int blk, int tid, int& grp, int& b, int& l){
  int c = (blk & 7) + 8*(blk >> 8);
  grp = (blk >> 3) & 31;
  if(c >= CH) return false;
  int gidx = c*256 + tid;
  if(gidx >= NPIX) return false;
  b = gidx / LPIX; l = gidx % LPIX;
  return true;
}

// XCD-pinned decode, 8 groups: blk = (c%8) + 8*g + 64*(c/8), grid 256.
DEV bool upix_xcd8(int blk, int tid, int& grp, int& b, int& l){
  int c = (blk & 7) + 8*(blk >> 6);
  grp = (blk >> 3) & 7;
  if(c >= CH) return false;
  int gidx = c*256 + tid;
  if(gidx >= NPIX) return false;
  b = gidx / LPIX; l = gidx % LPIX;
  return true;
}

// ================= bodies =================
// dw1t: zero-padded 34x34 LDS tile -> straight-line 7x7 conv (no bounds branches)
DEV void body_dw1t(int bc, int tid, float* xs, const float* X, const float* w, const float* bias, const float* bnp, float* out){
  int c = bc & 63, b = bc >> 6;
  const float* xp = X + ((size_t)(b*DIM+c))*LPIX;
  for(int i=tid;i<34*34;i+=256) xs[i]=0.f;
  __syncthreads();
  for(int i=tid;i<LPIX;i+=256){ int y=i/28, x=i%28; xs[(y+3)*34+(x+3)]=xp[i]; }
  __syncthreads();
  const float* wc = w + (size_t)c*49;
  float bs = bias[c];
  for(int i=tid;i<LPIX;i+=256){
    int y=i/28, x=i%28;
    float s = bs;
    #pragma unroll
    for(int ky=0;ky<7;ky++){
      #pragma unroll
      for(int kx=0;kx<7;kx++)
        s += xs[(y+ky)*34 + x+kx]*wc[ky*7+kx];
    }
    out[((size_t)(b*C+c))*LPIX + i] = bnorm(s,bnp,c,C);
  }
}

// branch2: round-16 form (r17 wave-split experiment regressed; reverted).
DEV void body_branch2(int bc, int tid, float* smem, const float* X,
                      const float* h1w,const float* v1w,const float* h2w,const float* v2w,
                      const float* bnp, float* xa){
  int c = bc & 63, b = bc >> 6;
  float* xs  = smem;
  float* mp  = smem+LPIX;
  float* xt  = smem+2*LPIX;
  float* attv= smem+2*LPIX+100;
  const float* xp = X + ((size_t)(b*DIM+64+c))*LPIX;
  for(int i=tid;i<LPIX;i+=256) xs[i]=xp[i];
  __syncthreads();
  for(int i=tid;i<LPIX;i+=256){
    int y=i/28, x=i%28;
    float m=-1e30f;
    for(int dy=-1;dy<=1;dy++){ int iy=y+dy; if(iy<0||iy>=28) continue;
      for(int dx=-1;dx<=1;dx++){ int ix=x+dx; if(ix<0||ix>=28) continue;
        m=fmaxf(m,xs[iy*28+ix]); } }
    mp[i]=m;
  }
  __syncthreads();
  if(tid<100){
    int ii=tid/10, j=tid%10;
    const float fw[4]={0.125f,0.375f,0.375f,0.125f};
    float s=0;
    for(int ky=0;ky<4;ky++){ int rr=refl(3*ii+ky);
      for(int kx=0;kx<4;kx++){ int cc=refl(3*j+kx);
        s += fw[ky]*fw[kx]*mp[rr*28+cc]; } }
    xt[tid]=s;
  }
  __syncthreads();
  if(tid<100){
    int r=tid/10, j=tid%10;
    float s=0;
    for(int kh=0;kh<11;kh++){ int a=r+kh-5; if(a<0||a>=10) continue;
      for(int kw=0;kw<3;kw++){ int b2=j+kw-1; if(b2<0||b2>=10) continue;
        s+=xt[a*10+b2]*h1w[(size_t)c*33+kh*3+kw]; } }
    for(int kh=0;kh<3;kh++){ int a=r+kh-1; if(a<0||a>=10) continue;
      for(int kw=0;kw<11;kw++){ int b2=j+kw-5; if(b2<0||b2>=10) continue;
        s+=xt[a*10+b2]*v1w[(size_t)c*33+kh*11+kw]; } }
    { int t=20*r+j; int r2=t/19, j2=t%19;
      for(int kh=0;kh<11;kh++){ int a=r2+kh-5; if(a<0||a>=10) continue;
        for(int kw=0;kw<3;kw++){ int b2=j2+kw-1; if(b2<0||b2>=19) continue;
          int i2=19*a+b2; int row=i2/20, col=i2%20;
          if(col<10) s+=xt[row*10+col]*h2w[(size_t)c*33+kh*3+kw]; } } }
    { int t=20*j+r; int p=t%19, q=t/19;
      for(int kh=0;kh<3;kh++){ int a=p+kh-1; if(a<0||a>=19) continue;
        for(int kw=0;kw<11;kw++){ int b2=q+kw-5; if(b2<0||b2>=10) continue;
          int i2=19*b2+a; int row=i2/20, col=i2%20;
          if(col<10) s+=xt[col*10+row]*v2w[(size_t)c*33+kh*11+kw]; } } }
    s = bnorm(s,bnp,c,C);
    attv[tid] = 1.f/(1.f+__expf(-s));
  }
  __syncthreads();
  float* dst = xa + ((size_t)(b*DIM+64+c))*LPIX;
  for(int i=tid;i<LPIX;i+=256){
    int y=i/28, x=i%28;
    float a = attv[((y*10)/28)*10 + (x*10)/28];
    dst[i] = xs[i]*a;
  }
}

// qkv: XCD-pinned; packed f32x2 math (pairs of input channels). grid 192.
DEV void body_qkv(int blk, int tid, const float* X, const float* w, float* qkvb){
  int c = (blk & 7) + 8*(blk/96);
  int og = (blk >> 3) % 12;
  if(c >= 13) return;
  int p0 = c*512 + tid;
  if(p0 >= NPIX) return;
  int o0 = og*16;
  int b0 = p0/LPIX, l0 = p0%LPIX;
  int p1 = p0 + 256;
  bool has1 = p1 < NPIX;
  int b1 = has1 ? p1/LPIX : b0, l1 = has1 ? p1%LPIX : l0;
  const float* xp0 = X + ((size_t)(b0*DIM+192))*LPIX + l0;
  const float* xp1 = X + ((size_t)(b1*DIM+192))*LPIX + l1;
  f32x2 s0[16], s1[16];
  #pragma unroll
  for(int t=0;t<16;t++){ s0[t]=0.f; s1[t]=0.f; }
  for(int cc=0;cc<C;cc+=4){
    f32x2 a01={xp0[(size_t)cc*LPIX],     xp0[(size_t)(cc+1)*LPIX]};
    f32x2 a23={xp0[(size_t)(cc+2)*LPIX], xp0[(size_t)(cc+3)*LPIX]};
    f32x2 e01={xp1[(size_t)cc*LPIX],     xp1[(size_t)(cc+1)*LPIX]};
    f32x2 e23={xp1[(size_t)(cc+2)*LPIX], xp1[(size_t)(cc+3)*LPIX]};
    #pragma unroll
    for(int t=0;t<16;t++){
      const float* wr = w + (size_t)(o0+t)*C + cc;
      f32x2 w01 = *(const f32x2*)(wr);
      f32x2 w23 = *(const f32x2*)(wr+2);
      s0[t] += w01*a01 + w23*a23;
      s1[t] += w01*e01 + w23*e23;
    }
  }
  int which=o0>>6, head0=(o0&63)>>2;
  #pragma unroll
  for(int t4=0;t4<4;t4++){
    float4* dst = (float4*)(qkvb + (size_t)which*B*NH*LPIX*HD + ((size_t)((b0*NH+head0+t4)*LPIX+l0))*HD);
    *dst = make_float4(s0[4*t4].x+s0[4*t4].y, s0[4*t4+1].x+s0[4*t4+1].y,
                       s0[4*t4+2].x+s0[4*t4+2].y, s0[4*t4+3].x+s0[4*t4+3].y);
  }
  if(has1){
    #pragma unroll
    for(int t4=0;t4<4;t4++){
      float4* dst = (float4*)(qkvb + (size_t)which*B*NH*LPIX*HD + ((size_t)((b1*NH+head0+t4)*LPIX+l1))*HD);
      *dst = make_float4(s1[4*t4].x+s1[4*t4].y, s1[4*t4+1].x+s1[4*t4+1].y,
                         s1[4*t4+2].x+s1[4*t4+2].y, s1[4*t4+3].x+s1[4*t4+3].y);
    }
  }
}

// bcdtssd: XCD-pinned on batch (b = blk&7); stage-1 packed f32x2. grid 384.
DEV void body_bcdtssd(int blk, int tid, float* smem, const float* X, const float* w, const float* dww,
                      float* bc2, float* wgt){
  int b = blk & 7, og = blk >> 3; int o0=og*4;
  float* bc1s = smem;            // 4*784
  const float* xp = X + ((size_t)(b*DIM+128))*LPIX;
  {
    int l0=tid, l1=tid+256, l2=tid+512;
    f32x2 acc0[4], acc1[4], acc2[4];
    #pragma unroll
    for(int t=0;t<4;t++){ acc0[t]=0.f; acc1[t]=0.f; acc2[t]=0.f; }
    for(int c=0;c<C;c+=4){
      f32x2 x0a={xp[(size_t)c*LPIX+l0],     xp[(size_t)(c+1)*LPIX+l0]};
      f32x2 x0b={xp[(size_t)(c+2)*LPIX+l0], xp[(size_t)(c+3)*LPIX+l0]};
      f32x2 x1a={xp[(size_t)c*LPIX+l1],     xp[(size_t)(c+1)*LPIX+l1]};
      f32x2 x1b={xp[(size_t)(c+2)*LPIX+l1], xp[(size_t)(c+3)*LPIX+l1]};
      f32x2 x2a={xp[(size_t)c*LPIX+l2],     xp[(size_t)(c+1)*LPIX+l2]};
      f32x2 x2b={xp[(size_t)(c+2)*LPIX+l2], xp[(size_t)(c+3)*LPIX+l2]};
      #pragma unroll
      for(int t=0;t<4;t++){
        const float* wr = w + (size_t)(o0+t)*C + c;
        f32x2 wa = *(const f32x2*)(wr);
        f32x2 wb = *(const f32x2*)(wr+2);
        acc0[t] += wa*x0a + wb*x0b;
        acc1[t] += wa*x1a + wb*x1b;
        acc2[t] += wa*x2a + wb*x2b;
      }
    }
    #pragma unroll
    for(int t=0;t<4;t++){
      bc1s[t*LPIX+l0]=acc0[t].x+acc0[t].y;
      bc1s[t*LPIX+l1]=acc1[t].x+acc1[t].y;
      bc1s[t*LPIX+l2]=acc2[t].x+acc2[t].y;
    }
    if(tid<16){
      int l=768+tid;
      f32x2 a0=0.f,a1=0.f,a2=0.f,a3=0.f;
      for(int c=0;c<C;c+=2){
        f32x2 xv={xp[(size_t)c*LPIX+l], xp[(size_t)(c+1)*LPIX+l]};
        a0 += (*(const f32x2*)(w + (size_t)(o0+0)*C + c))*xv;
        a1 += (*(const f32x2*)(w + (size_t)(o0+1)*C + c))*xv;
        a2 += (*(const f32x2*)(w + (size_t)(o0+2)*C + c))*xv;
        a3 += (*(const f32x2*)(w + (size_t)(o0+3)*C + c))*xv;
      }
      bc1s[0*LPIX+l]=a0.x+a0.y; bc1s[1*LPIX+l]=a1.x+a1.y;
      bc1s[2*LPIX+l]=a2.x+a2.y; bc1s[3*LPIX+l]=a3.x+a3.y;
    }
  }
  __syncthreads();
  if(og < 32){
    for(int i=tid;i<4*LPIX;i+=256){
      int oo=i/LPIX, l=i%LPIX; int y=l/28, x=l%28;
      const float* p = bc1s + oo*LPIX;
      const float* wk = dww + (size_t)(o0+oo)*9;
      float s=0;
      for(int ky=0;ky<3;ky++){ int iy=y+ky-1; if(iy<0||iy>=28) continue;
        for(int kx=0;kx<3;kx++){ int ix=x+kx-1; if(ix<0||ix>=28) continue;
          s += p[iy*28+ix]*wk[ky*3+kx]; } }
      bc2[((size_t)(b*192+o0+oo))*LPIX + l] = s;
    }
  } else {
    float cv[13];
    #pragma unroll
    for(int k=0;k<13;k++){
      int i = tid + k*256;
      if(i < 4*LPIX){
        int oo=i/LPIX, l=i%LPIX; int y=l/28, x=l%28;
        const float* p = bc1s + oo*LPIX;
        const float* wk = dww + (size_t)(o0+oo)*9;
        float s=0;
        for(int ky=0;ky<3;ky++){ int iy=y+ky-1; if(iy<0||iy>=28) continue;
          for(int kx=0;kx<3;kx++){ int ix=x+kx-1; if(ix<0||ix>=28) continue;
            s += p[iy*28+ix]*wk[ky*3+kx]; } }
        cv[k]=s;
      }
    }
    __syncthreads();
    #pragma unroll
    for(int k=0;k<13;k++){ int i=tid+k*256; if(i<4*LPIX) bc1s[i]=cv[k]; }
    __syncthreads();
    int wv = tid>>6, lane = tid&63;
    float* row = bc1s + wv*LPIX;
    float mx = -1e30f;
    for(int l=lane;l<LPIX;l+=64) mx = fmaxf(mx, row[l]);
    for(int off=32;off;off>>=1) mx = fmaxf(mx, __shfl_xor(mx,off));
    float sum=0;
    for(int l=lane;l<LPIX;l+=64){ float e=__expf(row[l]-mx); row[l]=e; sum+=e; }
    for(int off=32;off;off>>=1) sum += __shfl_xor(sum,off);
    float inv = 1.f/sum;
    int s_ = o0-128+wv;
    float* wp = wgt + ((size_t)(b*S+s_))*LPIX;
    for(int l=lane;l<LPIX;l+=64) wp[l] = row[l]*inv;
  }
}

// attn: packed-pair form (r14, proven). K/V pair-interleaved in LDS.
DEV void body_attn(int blk, int tid, float* kp, float* vp, const float* qkvb,
                   float* ob, float* lsb){
  int bh = blk >> 2, ms = blk & 3;
  int b = bh>>4, h = bh&15;
  const float4* q4 = (const float4*)(qkvb + (size_t)bh*LPIX*HD);
  const float4* k4 = (const float4*)(qkvb + (size_t)(B*NH + bh)*LPIX*HD) + ms*196;
  const float4* v4 = (const float4*)(qkvb + (size_t)(2*B*NH + bh)*LPIX*HD) + ms*196;
  for(int i=tid;i<196;i+=256){
    float4 kv=k4[i]; float4 vv=v4[i];
    int m=i>>1, e=i&1;
    float* kd = kp + m*8 + e;
    kd[0]=kv.x; kd[2]=kv.y; kd[4]=kv.z; kd[6]=kv.w;
    float* vd = vp + m*8 + e;
    vd[0]=vv.x; vd[2]=vv.y; vd[4]=vv.z; vd[6]=vv.w;
  }
  __syncthreads();
  const float SC = 0.5f*1.44269504f;
  float* obp = ob + (size_t)ms*B*LPIX*C;
  float* lsq = lsb + (size_t)ms*B*NH*LPIX + (size_t)bh*LPIX;

  float4 q[3];
  #pragma unroll
  for(int j=0;j<3;j++){
    float4 t = q4[tid + 256*j];
    q[j] = make_float4(t.x*SC, t.y*SC, t.z*SC, t.w*SC);
  }
  f32x2 l[3], ax[3], ay[3], az[3], aw[3];
  #pragma unroll
  for(int j=0;j<3;j++){ l[j]=0.f; ax[j]=0.f; ay[j]=0.f; az[j]=0.f; aw[j]=0.f; }
  for(int m=0;m<98;m++){
    float4 kxy = *(const float4*)(kp + m*8);
    float4 kzw = *(const float4*)(kp + m*8 + 4);
    float4 vxy = *(const float4*)(vp + m*8);
    float4 vzw = *(const float4*)(vp + m*8 + 4);
    f32x2 kx={kxy.x,kxy.y}, ky={kxy.z,kxy.w}, kz={kzw.x,kzw.y}, kw={kzw.z,kzw.w};
    f32x2 vx={vxy.x,vxy.y}, vy={vxy.z,vxy.w}, vz={vzw.x,vzw.y}, vw={vzw.z,vzw.w};
    #pragma unroll
    for(int j=0;j<3;j++){
      f32x2 sc = kx*q[j].x + ky*q[j].y + kz*q[j].z + kw*q[j].w;
      f32x2 p = { __builtin_amdgcn_exp2f(sc.x), __builtin_amdgcn_exp2f(sc.y) };
      l[j] += p;
      ax[j] += p*vx; ay[j] += p*vy; az[j] += p*vz; aw[j] += p*vw;
    }
  }
  #pragma unroll
  for(int j=0;j<3;j++){
    int r = tid + 256*j;
    *(float4*)(obp + ((size_t)(b*LPIX+r))*C + h*4) =
        make_float4(ax[j].x+ax[j].y, ay[j].x+ay[j].y, az[j].x+az[j].y, aw[j].x+aw[j].y);
    lsq[r] = l[j].x+l[j].y;
  }
  if(tid < 16){
    int r = 768 + tid;
    float4 t = q4[r];
    float4 qq = make_float4(t.x*SC,t.y*SC,t.z*SC,t.w*SC);
    f32x2 ls=0.f, bx=0.f, by=0.f, bz=0.f, bw=0.f;
    for(int m=0;m<98;m++){
      float4 kxy = *(const float4*)(kp + m*8);
      float4 kzw = *(const float4*)(kp + m*8 + 4);
      float4 vxy = *(const float4*)(vp + m*8);
      float4 vzw = *(const float4*)(vp + m*8 + 4);
      f32x2 kx={kxy.x,kxy.y}, ky={kxy.z,kxy.w}, kz={kzw.x,kzw.y}, kw={kzw.z,kzw.w};
      f32x2 vx={vxy.x,vxy.y}, vy={vxy.z,vxy.w}, vz={vzw.x,vzw.y}, vw={vzw.z,vzw.w};
      f32x2 sc = kx*qq.x + ky*qq.y + kz*qq.z + kw*qq.w;
      f32x2 p = { __builtin_amdgcn_exp2f(sc.x), __builtin_amdgcn_exp2f(sc.y) };
      ls += p; bx += p*vx; by += p*vy; bz += p*vz; bw += p*vw;
    }
    *(float4*)(obp + ((size_t)(b*LPIX+r))*C + h*4) =
        make_float4(bx.x+bx.y, by.x+by.y, bz.x+bz.y, bw.x+bw.y);
    lsq[r] = ls.x+ls.y;
  }
}

// star: XCD-pinned; packed f32x2 (4 pair-chunks per 8-wide step). grid 1024.
DEV void body_star(int blk, int tid, const float* x1o, const float* f1w,const float* f1b,const float* f2w,const float* f2b,float* t1){
  int jg, b, l; if(!upix_xcd32(blk, tid, jg, b, l)) return;
  int j0=jg*4;
  const float* xp = x1o + (size_t)b*C*LPIX + l;
  f32x2 a[4], g[4];
  #pragma unroll
  for(int t=0;t<4;t++){ a[t]=0.f; g[t]=0.f; }
  for(int c=0;c<C;c+=8){
    f32x2 xA={xp[(size_t)c*LPIX],     xp[(size_t)(c+1)*LPIX]};
    f32x2 xB={xp[(size_t)(c+2)*LPIX], xp[(size_t)(c+3)*LPIX]};
    f32x2 xC={xp[(size_t)(c+4)*LPIX], xp[(size_t)(c+5)*LPIX]};
    f32x2 xD={xp[(size_t)(c+6)*LPIX], xp[(size_t)(c+7)*LPIX]};
    #pragma unroll
    for(int t=0;t<4;t++){
      const float* f1r = f1w + (size_t)(j0+t)*C + c;
      const float* f2r = f2w + (size_t)(j0+t)*C + c;
      a[t] += (*(const f32x2*)(f1r))*xA + (*(const f32x2*)(f1r+2))*xB
            + (*(const f32x2*)(f1r+4))*xC + (*(const f32x2*)(f1r+6))*xD;
      g[t] += (*(const f32x2*)(f2r))*xA + (*(const f32x2*)(f2r+2))*xB
            + (*(const f32x2*)(f2r+4))*xC + (*(const f32x2*)(f2r+6))*xD;
    }
  }
  for(int t=0;t<4;t++){
    float av = fminf(fmaxf(a[t].x+a[t].y+f1b[j0+t],0.f),6.f);
    float gv = g[t].x+g[t].y+f2b[j0+t];
    t1[((size_t)(b*HID+j0+t))*LPIX + l] = av*gv;
  }
}

// gproj: XCD-pinned; packed f32x2. grid 256.
DEV void body_gproj(int blk, int tid, const float* t1, const float* gw,const float* gb,const float* bnp,float* t2){
  int cg, b, l; if(!upix_xcd8(blk, tid, cg, b, l)) return;
  int c0=cg*8;
  const float* tp = t1 + (size_t)b*HID*LPIX + l;
  f32x2 s[8];
  #pragma unroll
  for(int t=0;t<8;t++) s[t]=0.f;
  for(int j=0;j<HID;j+=4){
    f32x2 xA={tp[(size_t)j*LPIX],     tp[(size_t)(j+1)*LPIX]};
    f32x2 xB={tp[(size_t)(j+2)*LPIX], tp[(size_t)(j+3)*LPIX]};
    #pragma unroll
    for(int t=0;t<8;t++){
      const float* wr = gw + (size_t)(c0+t)*HID + j;
      s[t] += (*(const f32x2*)(wr))*xA + (*(const f32x2*)(wr+2))*xB;
    }
  }
  #pragma unroll
  for(int t=0;t<8;t++)
    t2[((size_t)(b*C+c0+t))*LPIX + l]=bnorm(s[t].x+s[t].y+gb[c0+t],bnp,c0+t,C);
}

// x4: XCD-pinned; packed f32x2 on the proj inner. grid 256.
DEV void body_x4(int blk, int tid, const float* X, const float* ob, const float* lsb,
                 const float* projw, const float* bnp, float* xa){
  int cg, b, l; if(!upix_xcd8(blk, tid, cg, b, l)) return;
  int c0=cg*8;
  const float* p0 = ob + ((size_t)(b*LPIX+l))*C;
  const float* p1 = p0 + (size_t)B*LPIX*C;
  const float* p2 = p1 + (size_t)B*LPIX*C;
  const float* p3 = p2 + (size_t)B*LPIX*C;
  f32x2 s[8];
  #pragma unroll
  for(int t=0;t<8;t++) s[t]=0.f;
  for(int h=0;h<NH;h++){
    size_t li = ((size_t)(b*NH+h))*LPIX + l;
    float lsum = lsb[li] + lsb[(size_t)B*NH*LPIX+li] + lsb[(size_t)2*B*NH*LPIX+li] + lsb[(size_t)3*B*NH*LPIX+li];
    float iv = 1.f/lsum;
    float4 q0=*(const float4*)(p0+h*4), q1=*(const float4*)(p1+h*4),
           q2=*(const float4*)(p2+h*4), q3=*(const float4*)(p3+h*4);
    f32x2 ovA = { (q0.x+q1.x+q2.x+q3.x)*iv, (q0.y+q1.y+q2.y+q3.y)*iv };
    f32x2 ovB = { (q0.z+q1.z+q2.z+q3.z)*iv, (q0.w+q1.w+q2.w+q3.w)*iv };
    const float* pw = projw + h*4;
    #pragma unroll
    for(int t=0;t<8;t++){
      const float* pr = pw + (size_t)(c0+t)*C;
      s[t] += (*(const f32x2*)(pr))*ovA + (*(const f32x2*)(pr+2))*ovB;
    }
  }
  #pragma unroll
  for(int t=0;t<8;t++){
    float v = s[t].x+s[t].y + X[((size_t)(b*DIM+192+c0+t))*LPIX + l];
    xa[((size_t)(b*DIM+192+c0+t))*LPIX + l] = bnorm(v,bnp,c0+t,C);
  }
}

// h: XCD-pinned on batch (b = blk&7); l-tile split into 2x98 halves. grid 512.
DEV void body_h(int blk, int tid, float* smem, const float* X, const float* wgt, const float* bc2, float* hq){
  int b = blk & 7, sub = blk >> 3;
  int tile = sub >> 2, qq = sub & 3;
  int ct = (tile>>2)*16, st = (tile&3)*16;
  float (*Xs)[99] = (float(*)[99])smem;
  float (*Ws)[99] = (float(*)[99])(smem + 16*99);
  int tc = tid>>4, ts = tid&15;
  float acc=0;
  #pragma unroll
  for(int half=0;half<2;half++){
    int lb = qq*196 + half*98;
    for(int i=tid;i<16*98;i+=256){
      int r=i/98, col=i%98;
      Xs[r][col] = X[((size_t)(b*DIM+128+ct+r))*LPIX + lb + col];
      Ws[r][col] = wgt[((size_t)(b*S+st+r))*LPIX + lb + col]
                 * bc2[((size_t)(b*192+st+r))*LPIX + lb + col];
    }
    __syncthreads();
    #pragma unroll 7
    for(int l=0;l<98;l++) acc += Xs[tc][l]*Ws[ts][l];
    __syncthreads();
  }
  hq[(size_t)qq*B*C*S + ((size_t)(b*C+ct+tc))*S + st+ts] = acc;
}

// dw2t: zero-padded 34x34 LDS tile, straight-line 7x7 conv
DEV void body_dw2t(int bc, int tid, float* xs, const float* t2, const float* w, const float* bias, float* xa){
  int c = bc & 63, b = bc >> 6;
  const float* tp = t2 + ((size_t)(b*C+c))*LPIX;
  for(int i=tid;i<34*34;i+=256) xs[i]=0.f;
  __syncthreads();
  for(int i=tid;i<LPIX;i+=256){ int y=i/28, x=i%28; xs[(y+3)*34+(x+3)]=tp[i]; }
  __syncthreads();
  const float* wc = w + (size_t)c*49;
  float bs = bias[c];
  for(int i=tid;i<LPIX;i+=256){
    int y=i/28, x=i%28;
    float s = bs;
    #pragma unroll
    for(int ky=0;ky<7;ky++){
      #pragma unroll
      for(int kx=0;kx<7;kx++)
        s += xs[(y+ky)*34 + x+kx]*wc[ky*7+kx];
    }
    xa[((size_t)(b*DIM+c))*LPIX + i] = s;
  }
}

DEV void body_mixho(int blk, int tid, float* smem, const float* hq, const float* hzw,
                    const float* Dp, const float* outw, float* ho){
  int b = blk >> 3, st = (blk & 7) * 8;
  float (*hs2)[8] = (float(*)[8])smem;
  float (*g1s)[8] = (float(*)[8])(smem + C*8);
  for(int i=tid;i<C*8;i+=256){
    int k=i>>3, si=i&7;
    size_t off = ((size_t)(b*C+k))*S + st + si;
    hs2[k][si] = hq[off] + hq[(size_t)B*C*S+off] + hq[(size_t)2*B*C*S+off] + hq[(size_t)3*B*C*S+off];
  }
  __syncthreads();
  float D = Dp[0];
  for(int i=tid;i<C*8;i+=256){
    int c=i>>3, si=i&7;
    float hv=0, zv=0;
    for(int k=0;k<C;k++){ float x=hs2[k][si]; hv+=hzw[(size_t)c*C+k]*x; zv+=hzw[(size_t)(C+c)*C+k]*x; }
    float sil = zv/(1.f+__expf(-zv));
    g1s[c][si]=hv*sil+hv*D;
  }
  __syncthreads();
  for(int i=tid;i<C*8;i+=256){
    int c=i>>3, si=i&7;
    float acc=0;
    for(int k=0;k<C;k++) acc+=outw[(size_t)c*C+k]*g1s[k][si];
    ho[((size_t)(b*C+c))*S + st + si]=acc;
  }
}

// x3: XCD-pinned; packed f32x2 (hp pairs are contiguous). grid 256.
DEV void body_x3(int blk, int tid, const float* ho, const float* bc2, float* xa){
  int cg, b, l; if(!upix_xcd8(blk, tid, cg, b, l)) return;
  int c0=cg*8;
  const float* hp = ho + (size_t)(b*C+c0)*S;
  const float* cm = bc2 + ((size_t)(b*192+64))*LPIX + l;
  f32x2 s[8];
  #pragma unroll
  for(int t=0;t<8;t++) s[t]=0.f;
  for(int s_=0;s_<S;s_+=2){
    f32x2 cv = { cm[(size_t)s_*LPIX], cm[(size_t)(s_+1)*LPIX] };
    #pragma unroll
    for(int t=0;t<8;t++)
      s[t] += (*(const f32x2*)(hp + (size_t)t*S + s_))*cv;
  }
  #pragma unroll
  for(int t=0;t<8;t++)
    xa[((size_t)(b*DIM+128+c0+t))*LPIX + l] = s[t].x+s[t].y;
}

// ================= stage kernels =================
// S1: [0,384)=bcdtssd  [384,896)=branch2  [896,1088)=qkv  [1088,1600)=dw1t
__global__ void k_s1(const float* X,
                     const float* bcdt_w, const float* ssd_dw, float* bc2, float* wgt,
                     const float* h1w,const float* v1w,const float* h2w,const float* v2w,const float* bn_mra,
                     const float* qkv_w, float* qkvb,
                     const float* dw1_w,const float* dw1_b,const float* bn_dw1,
                     float* xa, float* x1o){
  __shared__ float smem[4*LPIX];
  int blk = blockIdx.x, tid = threadIdx.x;
  if(blk < 384)            body_bcdtssd(blk, tid, smem, X, bcdt_w, ssd_dw, bc2, wgt);
  else if(blk < 896)       body_branch2(blk-384, tid, smem, X, h1w,v1w,h2w,v2w, bn_mra, xa);
  else if(blk < 1088)      body_qkv(blk-896, tid, X, qkv_w, qkvb);
  else                     body_dw1t(blk-1088, tid, smem, X, dw1_w, dw1_b, bn_dw1, x1o);
}

// S2: [0,512)=attn  [512,1536)=star  [1536,2048)=h   (LDS 3168 floats = 12.7KB)
__global__ void k_s2(const float* qkvb, float* ob, float* lsb,
                     const float* x1o, const float* f1w,const float* f1b,const float* f2w,const float* f2b, float* t1,
                     const float* X, const float* wgt, const float* bc2, float* hq){
  __shared__ float smem[3168];
  int blk = blockIdx.x, tid = threadIdx.x;
  if(blk < 512)            body_attn(blk, tid, smem, smem+784, qkvb, ob, lsb);
  else if(blk < 1536)      body_star(blk-512, tid, x1o, f1w,f1b,f2w,f2b, t1);
  else                     body_h(blk-1536, tid, smem, X, wgt, bc2, hq);
}

// S3: [0,64)=mixho  [64,320)=gproj  [320,576)=x4
__global__ void k_s3(const float* t1, const float* gw,const float* gb,const float* bn_g, float* t2,
                     const float* X, const float* ob, const float* lsb,
                     const float* projw, const float* bn_n4, float* xa,
                     const float* hq, const float* hzw, const float* Dp, const float* outw, float* ho){
  __shared__ float smem[2*C*8];
  int blk = blockIdx.x, tid = threadIdx.x;
  if(blk < 64)        body_mixho(blk, tid, smem, hq, hzw, Dp, outw, ho);
  else if(blk < 320)  body_gproj(blk-64, tid, t1, gw, gb, bn_g, t2);
  else                body_x4(blk-320, tid, X, ob, lsb, projw, bn_n4, xa);
}

// S4: [0,512)=dw2t  [512,768)=x3
__global__ void k_s4(const float* t2, const float* dw2_w, const float* dw2_b, float* xa,
                     const float* ho, const float* bc2){
  __shared__ float smem[34*34];
  int blk = blockIdx.x, tid = threadIdx.x;
  if(blk < 512) body_dw2t(blk, tid, smem, t2, dw2_w, dw2_b, xa);
  else          body_x3(blk-512, tid, ho, bc2, xa);
}

// mid: XCD-pinned; packed f32x2. grid 1024.
__global__ void k_mid(const float* xa, const float* m1w, const float* bnp, float* mid){
  int jg, b, l; if(!upix_xcd32(blockIdx.x, threadIdx.x, jg, b, l)) return;
  int j0=jg*4;
  const float* xp = xa + (size_t)b*DIM*LPIX + l;
  f32x2 s[4];
  #pragma unroll
  for(int t=0;t<4;t++) s[t]=0.f;
  for(int c=0;c<DIM;c+=8){
    f32x2 xA={xp[(size_t)c*LPIX],     xp[(size_t)(c+1)*LPIX]};
    f32x2 xB={xp[(size_t)(c+2)*LPIX], xp[(size_t)(c+3)*LPIX]};
    f32x2 xC={xp[(size_t)(c+4)*LPIX], xp[(size_t)(c+5)*LPIX]};
    f32x2 xD={xp[(size_t)(c+6)*LPIX], xp[(size_t)(c+7)*LPIX]};
    #pragma unroll
    for(int t=0;t<4;t++){
      const float* wr = m1w + (size_t)(j0+t)*DIM + c;
      s[t] += (*(const f32x2*)(wr))*xA + (*(const f32x2*)(wr+2))*xB
            + (*(const f32x2*)(wr+4))*xC + (*(const f32x2*)(wr+6))*xD;
    }
  }
  for(int t=0;t<4;t++)
    mid[((size_t)(b*HID+j0+t))*LPIX + l] = fmaxf(bnorm(s[t].x+s[t].y,bnp,j0+t,HID),0.f);
}

// out: XCD-pinned; packed f32x2. grid 1024.
__global__ void k_out(const float* X, const float* mid, const float* m2w, const float* bnp, float* out){
  int cg, b, l; if(!upix_xcd32(blockIdx.x, threadIdx.x, cg, b, l)) return;
  int c0=cg*8;
  const float* mp_ = mid + (size_t)b*HID*LPIX + l;
  f32x2 s[8];
  #pragma unroll
  for(int t=0;t<8;t++) s[t]=0.f;
  for(int j=0;j<HID;j+=8){
    f32x2 mA={mp_[(size_t)j*LPIX],     mp_[(size_t)(j+1)*LPIX]};
    f32x2 mB={mp_[(size_t)(j+2)*LPIX], mp_[(size_t)(j+3)*LPIX]};
    f32x2 mC={mp_[(size_t)(j+4)*LPIX], mp_[(size_t)(j+5)*LPIX]};
    f32x2 mD={mp_[(size_t)(j+6)*LPIX], mp_[(size_t)(j+7)*LPIX]};
    #pragma unroll
    for(int t=0;t<8;t++){
      const float* wr = m2w + (size_t)(c0+t)*HID + j;
      s[t] += (*(const f32x2*)(wr))*mA + (*(const f32x2*)(wr+2))*mB
            + (*(const f32x2*)(wr+4))*mC + (*(const f32x2*)(wr+6))*mD;
    }
  }
  for(int t=0;t<8;t++){
    size_t oi = ((size_t)(b*DIM+c0+t))*LPIX + l;
    out[oi] = bnorm(s[t].x+s[t].y,bnp,c0+t,DIM) + X[oi];
  }
}

extern "C" void kernel_launch(void* const* d_in, const int* in_sizes, int n_in,
                              void* d_out, int out_size, void* d_ws, size_t ws_size,
                              hipStream_t stream) {
  const float* X      = (const float*)d_in[0];
  const float* dw1_w  = (const float*)d_in[1];
  const float* dw1_b  = (const float*)d_in[2];
  const float* bn_dw1 = (const float*)d_in[3];
  const float* f1_w   = (const float*)d_in[4];
  const float* f1_b   = (const float*)d_in[5];
  const float* f2_w   = (const float*)d_in[6];
  const float* f2_b   = (const float*)d_in[7];
  const float* g_w    = (const float*)d_in[8];
  const float* g_b    = (const float*)d_in[9];
  const float* bn_g   = (const float*)d_in[10];
  const float* dw2_w  = (const float*)d_in[11];
  const float* dw2_b  = (const float*)d_in[12];
  const float* hatt1w = (const float*)d_in[13];
  const float* vatt1w = (const float*)d_in[14];
  const float* hatt2w = (const float*)d_in[15];
  const float* vatt2w = (const float*)d_in[16];
  const float* bn_mra = (const float*)d_in[17];
  const float* bcdt_w = (const float*)d_in[18];
  const float* ssd_dw = (const float*)d_in[19];
  const float* hz_w   = (const float*)d_in[20];
  const float* out_w  = (const float*)d_in[21];
  const float* D_p    = (const float*)d_in[23];
  const float* qkv_w  = (const float*)d_in[24];
  const float* proj_w = (const float*)d_in[25];
  const float* bn_n4  = (const float*)d_in[26];
  const float* mlp1_w = (const float*)d_in[27];
  const float* bn_mlp = (const float*)d_in[28];
  const float* mlp2_w = (const float*)d_in[29];
  const float* bn_n1  = (const float*)d_in[30];

  float* ws   = (float*)d_ws;
  float* x1o  = ws+OFF_X1O;  float* t1  = ws+OFF_T1;  float* t2  = ws+OFF_T2;
  float* xa   = ws+OFF_XA;   float* bc2 = ws+OFF_BC2; float* wgt = ws+OFF_WGT;
  float* hq   = ws+OFF_H;    float* ho  = ws+OFF_HO;  float* qkvb= ws+OFF_QKV;
  float* ob   = ws+OFF_O;    float* lsb = ws+OFF_LS;  float* mid = ws+OFF_MID;

  dim3 blk(256);

  k_s1 <<<dim3(1600),blk,0,stream>>>(X, bcdt_w, ssd_dw, bc2, wgt,
                                     hatt1w,vatt1w,hatt2w,vatt2w,bn_mra,
                                     qkv_w, qkvb, dw1_w,dw1_b,bn_dw1, xa, x1o);
  k_s2 <<<dim3(2048),blk,0,stream>>>(qkvb, ob, lsb,
                                     x1o, f1_w,f1_b,f2_w,f2_b, t1,
                                     X, wgt, bc2, hq);
  k_s3 <<<dim3(576),blk,0,stream>>>(t1, g_w,g_b,bn_g, t2,
                                     X, ob, lsb, proj_w, bn_n4, xa,
                                     hq, hz_w, D_p, out_w, ho);
  k_s4 <<<dim3(768),blk,0,stream>>>(t2, dw2_w, dw2_b, xa, ho, bc2);
  k_mid<<<dim3(1024),blk,0,stream>>>(xa,mlp1_w,bn_mlp,mid);
  k_out<<<dim3(1024),blk,0,stream>>>(X,mid,mlp2_w,bn_n1,(float*)d_out);
}

// Round 20
// 246.939 us; speedup vs baseline: 1.0122x; 1.0001x over previous
//
#include <hip/hip_runtime.h>
#include <hip/hip_bf16.h>
#include <math.h>

#define DEV __device__ __forceinline__

typedef float f32x2 __attribute__((ext_vector_type(2)));

constexpr int B=8, C=64, DIM=256, HID=128, S=64, NH=16, HD=4, LPIX=784;
constexpr int NPIX = B*LPIX;          // 6272
constexpr int CH   = (NPIX+255)/256;  // 25

constexpr size_t OFF_X1O = 0;
constexpr size_t OFF_T1  = OFF_X1O + (size_t)B*C*LPIX;
constexpr size_t OFF_T2  = OFF_T1  + (size_t)B*HID*LPIX;
constexpr size_t OFF_XA  = OFF_T2  + (size_t)B*C*LPIX;
constexpr size_t OFF_BC2 = OFF_XA  + (size_t)B*DIM*LPIX;
constexpr size_t OFF_WGT = OFF_BC2 + (size_t)B*192*LPIX;        // B*S*L (pure softmax probs)
constexpr size_t OFF_H   = OFF_WGT + (size_t)B*S*LPIX;          // 4 * B*C*S
constexpr size_t OFF_HO  = OFF_H   + (size_t)4*B*C*S;
constexpr size_t OFF_QKV = OFF_HO  + (size_t)B*C*S;
constexpr size_t OFF_O   = OFF_QKV + (size_t)3*B*NH*LPIX*HD;    // 4 * B*L*C partials
constexpr size_t OFF_LS  = OFF_O   + (size_t)4*B*LPIX*C;        // 4 * B*NH*L
constexpr size_t OFF_MID = OFF_LS  + (size_t)4*B*NH*LPIX;

DEV float bnorm(float x, const float* p, int c, int nc){
  float g=p[c], bb=p[nc+c], m=p[2*nc+c], v=p[3*nc+c];
  return (x-m)*(g*rsqrtf(v+1e-5f))+bb;
}
DEV int refl(int p){ int k=p-1; if(k<0)k=-k; if(k>27)k=54-k; return k; }

// XCD-pinned decode, 32 groups: blk = (c%8) + 8*g + 256*(c/8), grid 1024.
DEV bool upix_xcd32(int blk, int tid, int& grp, int& b, int& l){
  int c = (blk & 7) + 8*(blk >> 8);
  grp = (blk >> 3) & 31;
  if(c >= CH) return false;
  int gidx = c*256 + tid;
  if(gidx >= NPIX) return false;
  b = gidx / LPIX; l = gidx % LPIX;
  return true;
}

// XCD-pinned decode, 8 groups: blk = (c%8) + 8*g + 64*(c/8), grid 256.
DEV bool upix_xcd8(int blk, int tid, int& grp, int& b, int& l){
  int c = (blk & 7) + 8*(blk >> 6);
  grp = (blk >> 3) & 7;
  if(c >= CH) return false;
  int gidx = c*256 + tid;
  if(gidx >= NPIX) return false;
  b = gidx / LPIX; l = gidx % LPIX;
  return true;
}

// 7x7 depthwise conv over a zero-padded 34x40 LDS tile (left-pad 4 for 16B
// alignment). Each thread computes a horizontal run of 4 adjacent pixels:
// per conv row, one f4+f4+f2 vector load (3 LDS instrs) feeds all 4 outputs.
// Critical path: 21 vector LDS reads vs 196 scalar (old). Tap order per pixel
// unchanged (ky-major, kx-minor).
DEV void dw7x7(int tid, const float* xs, const float* wc, float bs, float4& o){
  int row = tid/7, x0 = (tid%7)*4;
  float a0=bs, a1=bs, a2=bs, a3=bs;
  #pragma unroll
  for(int ky=0;ky<7;ky++){
    const float* rp = xs + (row+ky)*40 + x0 + 4;
    float4 va = *(const float4*)(rp);
    float4 vb = *(const float4*)(rp+4);
    f32x2 vc = *(const f32x2*)(rp+8);
    float r[10] = {va.x,va.y,va.z,va.w, vb.x,vb.y,vb.z,vb.w, vc.x,vc.y};
    #pragma unroll
    for(int kx=0;kx<7;kx++){
      float w = wc[ky*7+kx];
      a0 += r[kx]*w; a1 += r[kx+1]*w; a2 += r[kx+2]*w; a3 += r[kx+3]*w;
    }
  }
  o = make_float4(a0,a1,a2,a3);
}

// ================= bodies =================
// dw1t: padded 34x40 LDS tile, 4-px register-blocked 7x7 conv, float4 store
DEV void body_dw1t(int bc, int tid, float* xs, const float* X, const float* w, const float* bias, const float* bnp, float* out){
  int c = bc & 63, b = bc >> 6;
  const float* xp = X + ((size_t)(b*DIM+c))*LPIX;
  for(int i=tid;i<34*40;i+=256) xs[i]=0.f;
  __syncthreads();
  for(int i=tid;i<LPIX;i+=256){ int y=i/28, x=i%28; xs[(y+3)*40+(x+4)]=xp[i]; }
  __syncthreads();
  if(tid < 196){
    const float* wc = w + (size_t)c*49;
    float4 o;
    dw7x7(tid, xs, wc, bias[c], o);
    o.x = bnorm(o.x,bnp,c,C); o.y = bnorm(o.y,bnp,c,C);
    o.z = bnorm(o.z,bnp,c,C); o.w = bnorm(o.w,bnp,c,C);
    int row = tid/7, x0 = (tid%7)*4;
    *(float4*)(out + ((size_t)(b*C+c))*LPIX + row*28 + x0) = o;
  }
}

// branch2: round-16 form (r17 wave-split experiment regressed; reverted).
DEV void body_branch2(int bc, int tid, float* smem, const float* X,
                      const float* h1w,const float* v1w,const float* h2w,const float* v2w,
                      const float* bnp, float* xa){
  int c = bc & 63, b = bc >> 6;
  float* xs  = smem;
  float* mp  = smem+LPIX;
  float* xt  = smem+2*LPIX;
  float* attv= smem+2*LPIX+100;
  const float* xp = X + ((size_t)(b*DIM+64+c))*LPIX;
  for(int i=tid;i<LPIX;i+=256) xs[i]=xp[i];
  __syncthreads();
  for(int i=tid;i<LPIX;i+=256){
    int y=i/28, x=i%28;
    float m=-1e30f;
    for(int dy=-1;dy<=1;dy++){ int iy=y+dy; if(iy<0||iy>=28) continue;
      for(int dx=-1;dx<=1;dx++){ int ix=x+dx; if(ix<0||ix>=28) continue;
        m=fmaxf(m,xs[iy*28+ix]); } }
    mp[i]=m;
  }
  __syncthreads();
  if(tid<100){
    int ii=tid/10, j=tid%10;
    const float fw[4]={0.125f,0.375f,0.375f,0.125f};
    float s=0;
    for(int ky=0;ky<4;ky++){ int rr=refl(3*ii+ky);
      for(int kx=0;kx<4;kx++){ int cc=refl(3*j+kx);
        s += fw[ky]*fw[kx]*mp[rr*28+cc]; } }
    xt[tid]=s;
  }
  __syncthreads();
  if(tid<100){
    int r=tid/10, j=tid%10;
    float s=0;
    for(int kh=0;kh<11;kh++){ int a=r+kh-5; if(a<0||a>=10) continue;
      for(int kw=0;kw<3;kw++){ int b2=j+kw-1; if(b2<0||b2>=10) continue;
        s+=xt[a*10+b2]*h1w[(size_t)c*33+kh*3+kw]; } }
    for(int kh=0;kh<3;kh++){ int a=r+kh-1; if(a<0||a>=10) continue;
      for(int kw=0;kw<11;kw++){ int b2=j+kw-5; if(b2<0||b2>=10) continue;
        s+=xt[a*10+b2]*v1w[(size_t)c*33+kh*11+kw]; } }
    { int t=20*r+j; int r2=t/19, j2=t%19;
      for(int kh=0;kh<11;kh++){ int a=r2+kh-5; if(a<0||a>=10) continue;
        for(int kw=0;kw<3;kw++){ int b2=j2+kw-1; if(b2<0||b2>=19) continue;
          int i2=19*a+b2; int row=i2/20, col=i2%20;
          if(col<10) s+=xt[row*10+col]*h2w[(size_t)c*33+kh*3+kw]; } } }
    { int t=20*j+r; int p=t%19, q=t/19;
      for(int kh=0;kh<3;kh++){ int a=p+kh-1; if(a<0||a>=19) continue;
        for(int kw=0;kw<11;kw++){ int b2=q+kw-5; if(b2<0||b2>=10) continue;
          int i2=19*b2+a; int row=i2/20, col=i2%20;
          if(col<10) s+=xt[col*10+row]*v2w[(size_t)c*33+kh*11+kw]; } } }
    s = bnorm(s,bnp,c,C);
    attv[tid] = 1.f/(1.f+__expf(-s));
  }
  __syncthreads();
  float* dst = xa + ((size_t)(b*DIM+64+c))*LPIX;
  for(int i=tid;i<LPIX;i+=256){
    int y=i/28, x=i%28;
    float a = attv[((y*10)/28)*10 + (x*10)/28];
    dst[i] = xs[i]*a;
  }
}

// qkv: XCD-pinned; packed f32x2 math (pairs of input channels). grid 192.
DEV void body_qkv(int blk, int tid, const float* X, const float* w, float* qkvb){
  int c = (blk & 7) + 8*(blk/96);
  int og = (blk >> 3) % 12;
  if(c >= 13) return;
  int p0 = c*512 + tid;
  if(p0 >= NPIX) return;
  int o0 = og*16;
  int b0 = p0/LPIX, l0 = p0%LPIX;
  int p1 = p0 + 256;
  bool has1 = p1 < NPIX;
  int b1 = has1 ? p1/LPIX : b0, l1 = has1 ? p1%LPIX : l0;
  const float* xp0 = X + ((size_t)(b0*DIM+192))*LPIX + l0;
  const float* xp1 = X + ((size_t)(b1*DIM+192))*LPIX + l1;
  f32x2 s0[16], s1[16];
  #pragma unroll
  for(int t=0;t<16;t++){ s0[t]=0.f; s1[t]=0.f; }
  for(int cc=0;cc<C;cc+=4){
    f32x2 a01={xp0[(size_t)cc*LPIX],     xp0[(size_t)(cc+1)*LPIX]};
    f32x2 a23={xp0[(size_t)(cc+2)*LPIX], xp0[(size_t)(cc+3)*LPIX]};
    f32x2 e01={xp1[(size_t)cc*LPIX],     xp1[(size_t)(cc+1)*LPIX]};
    f32x2 e23={xp1[(size_t)(cc+2)*LPIX], xp1[(size_t)(cc+3)*LPIX]};
    #pragma unroll
    for(int t=0;t<16;t++){
      const float* wr = w + (size_t)(o0+t)*C + cc;
      f32x2 w01 = *(const f32x2*)(wr);
      f32x2 w23 = *(const f32x2*)(wr+2);
      s0[t] += w01*a01 + w23*a23;
      s1[t] += w01*e01 + w23*e23;
    }
  }
  int which=o0>>6, head0=(o0&63)>>2;
  #pragma unroll
  for(int t4=0;t4<4;t4++){
    float4* dst = (float4*)(qkvb + (size_t)which*B*NH*LPIX*HD + ((size_t)((b0*NH+head0+t4)*LPIX+l0))*HD);
    *dst = make_float4(s0[4*t4].x+s0[4*t4].y, s0[4*t4+1].x+s0[4*t4+1].y,
                       s0[4*t4+2].x+s0[4*t4+2].y, s0[4*t4+3].x+s0[4*t4+3].y);
  }
  if(has1){
    #pragma unroll
    for(int t4=0;t4<4;t4++){
      float4* dst = (float4*)(qkvb + (size_t)which*B*NH*LPIX*HD + ((size_t)((b1*NH+head0+t4)*LPIX+l1))*HD);
      *dst = make_float4(s1[4*t4].x+s1[4*t4].y, s1[4*t4+1].x+s1[4*t4+1].y,
                         s1[4*t4+2].x+s1[4*t4+2].y, s1[4*t4+3].x+s1[4*t4+3].y);
    }
  }
}

// bcdtssd: XCD-pinned on batch (b = blk&7); stage-1 packed f32x2. grid 384.
DEV void body_bcdtssd(int blk, int tid, float* smem, const float* X, const float* w, const float* dww,
                      float* bc2, float* wgt){
  int b = blk & 7, og = blk >> 3; int o0=og*4;
  float* bc1s = smem;            // 4*784
  const float* xp = X + ((size_t)(b*DIM+128))*LPIX;
  {
    int l0=tid, l1=tid+256, l2=tid+512;
    f32x2 acc0[4], acc1[4], acc2[4];
    #pragma unroll
    for(int t=0;t<4;t++){ acc0[t]=0.f; acc1[t]=0.f; acc2[t]=0.f; }
    for(int c=0;c<C;c+=4){
      f32x2 x0a={xp[(size_t)c*LPIX+l0],     xp[(size_t)(c+1)*LPIX+l0]};
      f32x2 x0b={xp[(size_t)(c+2)*LPIX+l0], xp[(size_t)(c+3)*LPIX+l0]};
      f32x2 x1a={xp[(size_t)c*LPIX+l1],     xp[(size_t)(c+1)*LPIX+l1]};
      f32x2 x1b={xp[(size_t)(c+2)*LPIX+l1], xp[(size_t)(c+3)*LPIX+l1]};
      f32x2 x2a={xp[(size_t)c*LPIX+l2],     xp[(size_t)(c+1)*LPIX+l2]};
      f32x2 x2b={xp[(size_t)(c+2)*LPIX+l2], xp[(size_t)(c+3)*LPIX+l2]};
      #pragma unroll
      for(int t=0;t<4;t++){
        const float* wr = w + (size_t)(o0+t)*C + c;
        f32x2 wa = *(const f32x2*)(wr);
        f32x2 wb = *(const f32x2*)(wr+2);
        acc0[t] += wa*x0a + wb*x0b;
        acc1[t] += wa*x1a + wb*x1b;
        acc2[t] += wa*x2a + wb*x2b;
      }
    }
    #pragma unroll
    for(int t=0;t<4;t++){
      bc1s[t*LPIX+l0]=acc0[t].x+acc0[t].y;
      bc1s[t*LPIX+l1]=acc1[t].x+acc1[t].y;
      bc1s[t*LPIX+l2]=acc2[t].x+acc2[t].y;
    }
    if(tid<16){
      int l=768+tid;
      f32x2 a0=0.f,a1=0.f,a2=0.f,a3=0.f;
      for(int c=0;c<C;c+=2){
        f32x2 xv={xp[(size_t)c*LPIX+l], xp[(size_t)(c+1)*LPIX+l]};
        a0 += (*(const f32x2*)(w + (size_t)(o0+0)*C + c))*xv;
        a1 += (*(const f32x2*)(w + (size_t)(o0+1)*C + c))*xv;
        a2 += (*(const f32x2*)(w + (size_t)(o0+2)*C + c))*xv;
        a3 += (*(const f32x2*)(w + (size_t)(o0+3)*C + c))*xv;
      }
      bc1s[0*LPIX+l]=a0.x+a0.y; bc1s[1*LPIX+l]=a1.x+a1.y;
      bc1s[2*LPIX+l]=a2.x+a2.y; bc1s[3*LPIX+l]=a3.x+a3.y;
    }
  }
  __syncthreads();
  if(og < 32){
    for(int i=tid;i<4*LPIX;i+=256){
      int oo=i/LPIX, l=i%LPIX; int y=l/28, x=l%28;
      const float* p = bc1s + oo*LPIX;
      const float* wk = dww + (size_t)(o0+oo)*9;
      float s=0;
      for(int ky=0;ky<3;ky++){ int iy=y+ky-1; if(iy<0||iy>=28) continue;
        for(int kx=0;kx<3;kx++){ int ix=x+kx-1; if(ix<0||ix>=28) continue;
          s += p[iy*28+ix]*wk[ky*3+kx]; } }
      bc2[((size_t)(b*192+o0+oo))*LPIX + l] = s;
    }
  } else {
    float cv[13];
    #pragma unroll
    for(int k=0;k<13;k++){
      int i = tid + k*256;
      if(i < 4*LPIX){
        int oo=i/LPIX, l=i%LPIX; int y=l/28, x=l%28;
        const float* p = bc1s + oo*LPIX;
        const float* wk = dww + (size_t)(o0+oo)*9;
        float s=0;
        for(int ky=0;ky<3;ky++){ int iy=y+ky-1; if(iy<0||iy>=28) continue;
          for(int kx=0;kx<3;kx++){ int ix=x+kx-1; if(ix<0||ix>=28) continue;
            s += p[iy*28+ix]*wk[ky*3+kx]; } }
        cv[k]=s;
      }
    }
    __syncthreads();
    #pragma unroll
    for(int k=0;k<13;k++){ int i=tid+k*256; if(i<4*LPIX) bc1s[i]=cv[k]; }
    __syncthreads();
    int wv = tid>>6, lane = tid&63;
    float* row = bc1s + wv*LPIX;
    float mx = -1e30f;
    for(int l=lane;l<LPIX;l+=64) mx = fmaxf(mx, row[l]);
    for(int off=32;off;off>>=1) mx = fmaxf(mx, __shfl_xor(mx,off));
    float sum=0;
    for(int l=lane;l<LPIX;l+=64){ float e=__expf(row[l]-mx); row[l]=e; sum+=e; }
    for(int off=32;off;off>>=1) sum += __shfl_xor(sum,off);
    float inv = 1.f/sum;
    int s_ = o0-128+wv;
    float* wp = wgt + ((size_t)(b*S+s_))*LPIX;
    for(int l=lane;l<LPIX;l+=64) wp[l] = row[l]*inv;
  }
}

// attn: packed-pair form (r14, proven). K/V pair-interleaved in LDS.
DEV void body_attn(int blk, int tid, float* kp, float* vp, const float* qkvb,
                   float* ob, float* lsb){
  int bh = blk >> 2, ms = blk & 3;
  int b = bh>>4, h = bh&15;
  const float4* q4 = (const float4*)(qkvb + (size_t)bh*LPIX*HD);
  const float4* k4 = (const float4*)(qkvb + (size_t)(B*NH + bh)*LPIX*HD) + ms*196;
  const float4* v4 = (const float4*)(qkvb + (size_t)(2*B*NH + bh)*LPIX*HD) + ms*196;
  for(int i=tid;i<196;i+=256){
    float4 kv=k4[i]; float4 vv=v4[i];
    int m=i>>1, e=i&1;
    float* kd = kp + m*8 + e;
    kd[0]=kv.x; kd[2]=kv.y; kd[4]=kv.z; kd[6]=kv.w;
    float* vd = vp + m*8 + e;
    vd[0]=vv.x; vd[2]=vv.y; vd[4]=vv.z; vd[6]=vv.w;
  }
  __syncthreads();
  const float SC = 0.5f*1.44269504f;
  float* obp = ob + (size_t)ms*B*LPIX*C;
  float* lsq = lsb + (size_t)ms*B*NH*LPIX + (size_t)bh*LPIX;

  float4 q[3];
  #pragma unroll
  for(int j=0;j<3;j++){
    float4 t = q4[tid + 256*j];
    q[j] = make_float4(t.x*SC, t.y*SC, t.z*SC, t.w*SC);
  }
  f32x2 l[3], ax[3], ay[3], az[3], aw[3];
  #pragma unroll
  for(int j=0;j<3;j++){ l[j]=0.f; ax[j]=0.f; ay[j]=0.f; az[j]=0.f; aw[j]=0.f; }
  for(int m=0;m<98;m++){
    float4 kxy = *(const float4*)(kp + m*8);
    float4 kzw = *(const float4*)(kp + m*8 + 4);
    float4 vxy = *(const float4*)(vp + m*8);
    float4 vzw = *(const float4*)(vp + m*8 + 4);
    f32x2 kx={kxy.x,kxy.y}, ky={kxy.z,kxy.w}, kz={kzw.x,kzw.y}, kw={kzw.z,kzw.w};
    f32x2 vx={vxy.x,vxy.y}, vy={vxy.z,vxy.w}, vz={vzw.x,vzw.y}, vw={vzw.z,vzw.w};
    #pragma unroll
    for(int j=0;j<3;j++){
      f32x2 sc = kx*q[j].x + ky*q[j].y + kz*q[j].z + kw*q[j].w;
      f32x2 p = { __builtin_amdgcn_exp2f(sc.x), __builtin_amdgcn_exp2f(sc.y) };
      l[j] += p;
      ax[j] += p*vx; ay[j] += p*vy; az[j] += p*vz; aw[j] += p*vw;
    }
  }
  #pragma unroll
  for(int j=0;j<3;j++){
    int r = tid + 256*j;
    *(float4*)(obp + ((size_t)(b*LPIX+r))*C + h*4) =
        make_float4(ax[j].x+ax[j].y, ay[j].x+ay[j].y, az[j].x+az[j].y, aw[j].x+aw[j].y);
    lsq[r] = l[j].x+l[j].y;
  }
  if(tid < 16){
    int r = 768 + tid;
    float4 t = q4[r];
    float4 qq = make_float4(t.x*SC,t.y*SC,t.z*SC,t.w*SC);
    f32x2 ls=0.f, bx=0.f, by=0.f, bz=0.f, bw=0.f;
    for(int m=0;m<98;m++){
      float4 kxy = *(const float4*)(kp + m*8);
      float4 kzw = *(const float4*)(kp + m*8 + 4);
      float4 vxy = *(const float4*)(vp + m*8);
      float4 vzw = *(const float4*)(vp + m*8 + 4);
      f32x2 kx={kxy.x,kxy.y}, ky={kxy.z,kxy.w}, kz={kzw.x,kzw.y}, kw={kzw.z,kzw.w};
      f32x2 vx={vxy.x,vxy.y}, vy={vxy.z,vxy.w}, vz={vzw.x,vzw.y}, vw={vzw.z,vzw.w};
      f32x2 sc = kx*qq.x + ky*qq.y + kz*qq.z + kw*qq.w;
      f32x2 p = { __builtin_amdgcn_exp2f(sc.x), __builtin_amdgcn_exp2f(sc.y) };
      ls += p; bx += p*vx; by += p*vy; bz += p*vz; bw += p*vw;
    }
    *(float4*)(obp + ((size_t)(b*LPIX+r))*C + h*4) =
        make_float4(bx.x+bx.y, by.x+by.y, bz.x+bz.y, bw.x+bw.y);
    lsq[r] = ls.x+ls.y;
  }
}

// star: XCD-pinned; packed f32x2 (4 pair-chunks per 8-wide step). grid 1024.
DEV void body_star(int blk, int tid, const float* x1o, const float* f1w,const float* f1b,const float* f2w,const float* f2b,float* t1){
  int jg, b, l; if(!upix_xcd32(blk, tid, jg, b, l)) return;
  int j0=jg*4;
  const float* xp = x1o + (size_t)b*C*LPIX + l;
  f32x2 a[4], g[4];
  #pragma unroll
  for(int t=0;t<4;t++){ a[t]=0.f; g[t]=0.f; }
  for(int c=0;c<C;c+=8){
    f32x2 xA={xp[(size_t)c*LPIX],     xp[(size_t)(c+1)*LPIX]};
    f32x2 xB={xp[(size_t)(c+2)*LPIX], xp[(size_t)(c+3)*LPIX]};
    f32x2 xC={xp[(size_t)(c+4)*LPIX], xp[(size_t)(c+5)*LPIX]};
    f32x2 xD={xp[(size_t)(c+6)*LPIX], xp[(size_t)(c+7)*LPIX]};
    #pragma unroll
    for(int t=0;t<4;t++){
      const float* f1r = f1w + (size_t)(j0+t)*C + c;
      const float* f2r = f2w + (size_t)(j0+t)*C + c;
      a[t] += (*(const f32x2*)(f1r))*xA + (*(const f32x2*)(f1r+2))*xB
            + (*(const f32x2*)(f1r+4))*xC + (*(const f32x2*)(f1r+6))*xD;
      g[t] += (*(const f32x2*)(f2r))*xA + (*(const f32x2*)(f2r+2))*xB
            + (*(const f32x2*)(f2r+4))*xC + (*(const f32x2*)(f2r+6))*xD;
    }
  }
  for(int t=0;t<4;t++){
    float av = fminf(fmaxf(a[t].x+a[t].y+f1b[j0+t],0.f),6.f);
    float gv = g[t].x+g[t].y+f2b[j0+t];
    t1[((size_t)(b*HID+j0+t))*LPIX + l] = av*gv;
  }
}

// gproj: XCD-pinned; packed f32x2. grid 256.
DEV void body_gproj(int blk, int tid, const float* t1, const float* gw,const float* gb,const float* bnp,float* t2){
  int cg, b, l; if(!upix_xcd8(blk, tid, cg, b, l)) return;
  int c0=cg*8;
  const float* tp = t1 + (size_t)b*HID*LPIX + l;
  f32x2 s[8];
  #pragma unroll
  for(int t=0;t<8;t++) s[t]=0.f;
  for(int j=0;j<HID;j+=4){
    f32x2 xA={tp[(size_t)j*LPIX],     tp[(size_t)(j+1)*LPIX]};
    f32x2 xB={tp[(size_t)(j+2)*LPIX], tp[(size_t)(j+3)*LPIX]};
    #pragma unroll
    for(int t=0;t<8;t++){
      const float* wr = gw + (size_t)(c0+t)*HID + j;
      s[t] += (*(const f32x2*)(wr))*xA + (*(const f32x2*)(wr+2))*xB;
    }
  }
  #pragma unroll
  for(int t=0;t<8;t++)
    t2[((size_t)(b*C+c0+t))*LPIX + l]=bnorm(s[t].x+s[t].y+gb[c0+t],bnp,c0+t,C);
}

// x4: XCD-pinned; packed f32x2 on the proj inner. grid 256.
DEV void body_x4(int blk, int tid, const float* X, const float* ob, const float* lsb,
                 const float* projw, const float* bnp, float* xa){
  int cg, b, l; if(!upix_xcd8(blk, tid, cg, b, l)) return;
  int c0=cg*8;
  const float* p0 = ob + ((size_t)(b*LPIX+l))*C;
  const float* p1 = p0 + (size_t)B*LPIX*C;
  const float* p2 = p1 + (size_t)B*LPIX*C;
  const float* p3 = p2 + (size_t)B*LPIX*C;
  f32x2 s[8];
  #pragma unroll
  for(int t=0;t<8;t++) s[t]=0.f;
  for(int h=0;h<NH;h++){
    size_t li = ((size_t)(b*NH+h))*LPIX + l;
    float lsum = lsb[li] + lsb[(size_t)B*NH*LPIX+li] + lsb[(size_t)2*B*NH*LPIX+li] + lsb[(size_t)3*B*NH*LPIX+li];
    float iv = 1.f/lsum;
    float4 q0=*(const float4*)(p0+h*4), q1=*(const float4*)(p1+h*4),
           q2=*(const float4*)(p2+h*4), q3=*(const float4*)(p3+h*4);
    f32x2 ovA = { (q0.x+q1.x+q2.x+q3.x)*iv, (q0.y+q1.y+q2.y+q3.y)*iv };
    f32x2 ovB = { (q0.z+q1.z+q2.z+q3.z)*iv, (q0.w+q1.w+q2.w+q3.w)*iv };
    const float* pw = projw + h*4;
    #pragma unroll
    for(int t=0;t<8;t++){
      const float* pr = pw + (size_t)(c0+t)*C;
      s[t] += (*(const f32x2*)(pr))*ovA + (*(const f32x2*)(pr+2))*ovB;
    }
  }
  #pragma unroll
  for(int t=0;t<8;t++){
    float v = s[t].x+s[t].y + X[((size_t)(b*DIM+192+c0+t))*LPIX + l];
    xa[((size_t)(b*DIM+192+c0+t))*LPIX + l] = bnorm(v,bnp,c0+t,C);
  }
}

// h: XCD-pinned on batch (b = blk&7); l-tile split into 2x98 halves. grid 512.
DEV void body_h(int blk, int tid, float* smem, const float* X, const float* wgt, const float* bc2, float* hq){
  int b = blk & 7, sub = blk >> 3;
  int tile = sub >> 2, qq = sub & 3;
  int ct = (tile>>2)*16, st = (tile&3)*16;
  float (*Xs)[99] = (float(*)[99])smem;
  float (*Ws)[99] = (float(*)[99])(smem + 16*99);
  int tc = tid>>4, ts = tid&15;
  float acc=0;
  #pragma unroll
  for(int half=0;half<2;half++){
    int lb = qq*196 + half*98;
    for(int i=tid;i<16*98;i+=256){
      int r=i/98, col=i%98;
      Xs[r][col] = X[((size_t)(b*DIM+128+ct+r))*LPIX + lb + col];
      Ws[r][col] = wgt[((size_t)(b*S+st+r))*LPIX + lb + col]
                 * bc2[((size_t)(b*192+st+r))*LPIX + lb + col];
    }
    __syncthreads();
    #pragma unroll 7
    for(int l=0;l<98;l++) acc += Xs[tc][l]*Ws[ts][l];
    __syncthreads();
  }
  hq[(size_t)qq*B*C*S + ((size_t)(b*C+ct+tc))*S + st+ts] = acc;
}

// dw2t: padded 34x40 LDS tile, 4-px register-blocked 7x7 conv, float4 store
DEV void body_dw2t(int bc, int tid, float* xs, const float* t2, const float* w, const float* bias, float* xa){
  int c = bc & 63, b = bc >> 6;
  const float* tp = t2 + ((size_t)(b*C+c))*LPIX;
  for(int i=tid;i<34*40;i+=256) xs[i]=0.f;
  __syncthreads();
  for(int i=tid;i<LPIX;i+=256){ int y=i/28, x=i%28; xs[(y+3)*40+(x+4)]=tp[i]; }
  __syncthreads();
  if(tid < 196){
    const float* wc = w + (size_t)c*49;
    float4 o;
    dw7x7(tid, xs, wc, bias[c], o);
    int row = tid/7, x0 = (tid%7)*4;
    *(float4*)(xa + ((size_t)(b*DIM+c))*LPIX + row*28 + x0) = o;
  }
}

DEV void body_mixho(int blk, int tid, float* smem, const float* hq, const float* hzw,
                    const float* Dp, const float* outw, float* ho){
  int b = blk >> 3, st = (blk & 7) * 8;
  float (*hs2)[8] = (float(*)[8])smem;
  float (*g1s)[8] = (float(*)[8])(smem + C*8);
  for(int i=tid;i<C*8;i+=256){
    int k=i>>3, si=i&7;
    size_t off = ((size_t)(b*C+k))*S + st + si;
    hs2[k][si] = hq[off] + hq[(size_t)B*C*S+off] + hq[(size_t)2*B*C*S+off] + hq[(size_t)3*B*C*S+off];
  }
  __syncthreads();
  float D = Dp[0];
  for(int i=tid;i<C*8;i+=256){
    int c=i>>3, si=i&7;
    float hv=0, zv=0;
    for(int k=0;k<C;k++){ float x=hs2[k][si]; hv+=hzw[(size_t)c*C+k]*x; zv+=hzw[(size_t)(C+c)*C+k]*x; }
    float sil = zv/(1.f+__expf(-zv));
    g1s[c][si]=hv*sil+hv*D;
  }
  __syncthreads();
  for(int i=tid;i<C*8;i+=256){
    int c=i>>3, si=i&7;
    float acc=0;
    for(int k=0;k<C;k++) acc+=outw[(size_t)c*C+k]*g1s[k][si];
    ho[((size_t)(b*C+c))*S + st + si]=acc;
  }
}

// x3: XCD-pinned; packed f32x2 (hp pairs are contiguous). grid 256.
DEV void body_x3(int blk, int tid, const float* ho, const float* bc2, float* xa){
  int cg, b, l; if(!upix_xcd8(blk, tid, cg, b, l)) return;
  int c0=cg*8;
  const float* hp = ho + (size_t)(b*C+c0)*S;
  const float* cm = bc2 + ((size_t)(b*192+64))*LPIX + l;
  f32x2 s[8];
  #pragma unroll
  for(int t=0;t<8;t++) s[t]=0.f;
  for(int s_=0;s_<S;s_+=2){
    f32x2 cv = { cm[(size_t)s_*LPIX], cm[(size_t)(s_+1)*LPIX] };
    #pragma unroll
    for(int t=0;t<8;t++)
      s[t] += (*(const f32x2*)(hp + (size_t)t*S + s_))*cv;
  }
  #pragma unroll
  for(int t=0;t<8;t++)
    xa[((size_t)(b*DIM+128+c0+t))*LPIX + l] = s[t].x+s[t].y;
}

// ================= stage kernels =================
// S1: [0,384)=bcdtssd  [384,896)=branch2  [896,1088)=qkv  [1088,1600)=dw1t
__global__ void k_s1(const float* X,
                     const float* bcdt_w, const float* ssd_dw, float* bc2, float* wgt,
                     const float* h1w,const float* v1w,const float* h2w,const float* v2w,const float* bn_mra,
                     const float* qkv_w, float* qkvb,
                     const float* dw1_w,const float* dw1_b,const float* bn_dw1,
                     float* xa, float* x1o){
  __shared__ float smem[4*LPIX];
  int blk = blockIdx.x, tid = threadIdx.x;
  if(blk < 384)            body_bcdtssd(blk, tid, smem, X, bcdt_w, ssd_dw, bc2, wgt);
  else if(blk < 896)       body_branch2(blk-384, tid, smem, X, h1w,v1w,h2w,v2w, bn_mra, xa);
  else if(blk < 1088)      body_qkv(blk-896, tid, X, qkv_w, qkvb);
  else                     body_dw1t(blk-1088, tid, smem, X, dw1_w, dw1_b, bn_dw1, x1o);
}

// S2: [0,512)=attn  [512,1536)=star  [1536,2048)=h   (LDS 3168 floats = 12.7KB)
__global__ void k_s2(const float* qkvb, float* ob, float* lsb,
                     const float* x1o, const float* f1w,const float* f1b,const float* f2w,const float* f2b, float* t1,
                     const float* X, const float* wgt, const float* bc2, float* hq){
  __shared__ float smem[3168];
  int blk = blockIdx.x, tid = threadIdx.x;
  if(blk < 512)            body_attn(blk, tid, smem, smem+784, qkvb, ob, lsb);
  else if(blk < 1536)      body_star(blk-512, tid, x1o, f1w,f1b,f2w,f2b, t1);
  else                     body_h(blk-1536, tid, smem, X, wgt, bc2, hq);
}

// S3: [0,64)=mixho  [64,320)=gproj  [320,576)=x4
__global__ void k_s3(const float* t1, const float* gw,const float* gb,const float* bn_g, float* t2,
                     const float* X, const float* ob, const float* lsb,
                     const float* projw, const float* bn_n4, float* xa,
                     const float* hq, const float* hzw, const float* Dp, const float* outw, float* ho){
  __shared__ float smem[2*C*8];
  int blk = blockIdx.x, tid = threadIdx.x;
  if(blk < 64)        body_mixho(blk, tid, smem, hq, hzw, Dp, outw, ho);
  else if(blk < 320)  body_gproj(blk-64, tid, t1, gw, gb, bn_g, t2);
  else                body_x4(blk-320, tid, X, ob, lsb, projw, bn_n4, xa);
}

// S4: [0,512)=dw2t  [512,768)=x3   (smem 34*40 for the padded conv tile)
__global__ void k_s4(const float* t2, const float* dw2_w, const float* dw2_b, float* xa,
                     const float* ho, const float* bc2){
  __shared__ float smem[34*40];
  int blk = blockIdx.x, tid = threadIdx.x;
  if(blk < 512) body_dw2t(blk, tid, smem, t2, dw2_w, dw2_b, xa);
  else          body_x3(blk-512, tid, ho, bc2, xa);
}

// mid: XCD-pinned; packed f32x2. grid 1024.
__global__ void k_mid(const float* xa, const float* m1w, const float* bnp, float* mid){
  int jg, b, l; if(!upix_xcd32(blockIdx.x, threadIdx.x, jg, b, l)) return;
  int j0=jg*4;
  const float* xp = xa + (size_t)b*DIM*LPIX + l;
  f32x2 s[4];
  #pragma unroll
  for(int t=0;t<4;t++) s[t]=0.f;
  for(int c=0;c<DIM;c+=8){
    f32x2 xA={xp[(size_t)c*LPIX],     xp[(size_t)(c+1)*LPIX]};
    f32x2 xB={xp[(size_t)(c+2)*LPIX], xp[(size_t)(c+3)*LPIX]};
    f32x2 xC={xp[(size_t)(c+4)*LPIX], xp[(size_t)(c+5)*LPIX]};
    f32x2 xD={xp[(size_t)(c+6)*LPIX], xp[(size_t)(c+7)*LPIX]};
    #pragma unroll
    for(int t=0;t<4;t++){
      const float* wr = m1w + (size_t)(j0+t)*DIM + c;
      s[t] += (*(const f32x2*)(wr))*xA + (*(const f32x2*)(wr+2))*xB
            + (*(const f32x2*)(wr+4))*xC + (*(const f32x2*)(wr+6))*xD;
    }
  }
  for(int t=0;t<4;t++)
    mid[((size_t)(b*HID+j0+t))*LPIX + l] = fmaxf(bnorm(s[t].x+s[t].y,bnp,j0+t,HID),0.f);
}

// out: XCD-pinned; packed f32x2. grid 1024.
__global__ void k_out(const float* X, const float* mid, const float* m2w, const float* bnp, float* out){
  int cg, b, l; if(!upix_xcd32(blockIdx.x, threadIdx.x, cg, b, l)) return;
  int c0=cg*8;
  const float* mp_ = mid + (size_t)b*HID*LPIX + l;
  f32x2 s[8];
  #pragma unroll
  for(int t=0;t<8;t++) s[t]=0.f;
  for(int j=0;j<HID;j+=8){
    f32x2 mA={mp_[(size_t)j*LPIX],     mp_[(size_t)(j+1)*LPIX]};
    f32x2 mB={mp_[(size_t)(j+2)*LPIX], mp_[(size_t)(j+3)*LPIX]};
    f32x2 mC={mp_[(size_t)(j+4)*LPIX], mp_[(size_t)(j+5)*LPIX]};
    f32x2 mD={mp_[(size_t)(j+6)*LPIX], mp_[(size_t)(j+7)*LPIX]};
    #pragma unroll
    for(int t=0;t<8;t++){
      const float* wr = m2w + (size_t)(c0+t)*HID + j;
      s[t] += (*(const f32x2*)(wr))*mA + (*(const f32x2*)(wr+2))*mB
            + (*(const f32x2*)(wr+4))*mC + (*(const f32x2*)(wr+6))*mD;
    }
  }
  for(int t=0;t<8;t++){
    size_t oi = ((size_t)(b*DIM+c0+t))*LPIX + l;
    out[oi] = bnorm(s[t].x+s[t].y,bnp,c0+t,DIM) + X[oi];
  }
}

extern "C" void kernel_launch(void* const* d_in, const int* in_sizes, int n_in,
                              void* d_out, int out_size, void* d_ws, size_t ws_size,
                              hipStream_t stream) {
  const float* X      = (const float*)d_in[0];
  const float* dw1_w  = (const float*)d_in[1];
  const float* dw1_b  = (const float*)d_in[2];
  const float* bn_dw1 = (const float*)d_in[3];
  const float* f1_w   = (const float*)d_in[4];
  const float* f1_b   = (const float*)d_in[5];
  const float* f2_w   = (const float*)d_in[6];
  const float* f2_b   = (const float*)d_in[7];
  const float* g_w    = (const float*)d_in[8];
  const float* g_b    = (const float*)d_in[9];
  const float* bn_g   = (const float*)d_in[10];
  const float* dw2_w  = (const float*)d_in[11];
  const float* dw2_b  = (const float*)d_in[12];
  const float* hatt1w = (const float*)d_in[13];
  const float* vatt1w = (const float*)d_in[14];
  const float* hatt2w = (const float*)d_in[15];
  const float* vatt2w = (const float*)d_in[16];
  const float* bn_mra = (const float*)d_in[17];
  const float* bcdt_w = (const float*)d_in[18];
  const float* ssd_dw = (const float*)d_in[19];
  const float* hz_w   = (const float*)d_in[20];
  const float* out_w  = (const float*)d_in[21];
  const float* D_p    = (const float*)d_in[23];
  const float* qkv_w  = (const float*)d_in[24];
  const float* proj_w = (const float*)d_in[25];
  const float* bn_n4  = (const float*)d_in[26];
  const float* mlp1_w = (const float*)d_in[27];
  const float* bn_mlp = (const float*)d_in[28];
  const float* mlp2_w = (const float*)d_in[29];
  const float* bn_n1  = (const float*)d_in[30];

  float* ws   = (float*)d_ws;
  float* x1o  = ws+OFF_X1O;  float* t1  = ws+OFF_T1;  float* t2  = ws+OFF_T2;
  float* xa   = ws+OFF_XA;   float* bc2 = ws+OFF_BC2; float* wgt = ws+OFF_WGT;
  float* hq   = ws+OFF_H;    float* ho  = ws+OFF_HO;  float* qkvb= ws+OFF_QKV;
  float* ob   = ws+OFF_O;    float* lsb = ws+OFF_LS;  float* mid = ws+OFF_MID;

  dim3 blk(256);

  k_s1 <<<dim3(1600),blk,0,stream>>>(X, bcdt_w, ssd_dw, bc2, wgt,
                                     hatt1w,vatt1w,hatt2w,vatt2w,bn_mra,
                                     qkv_w, qkvb, dw1_w,dw1_b,bn_dw1, xa, x1o);
  k_s2 <<<dim3(2048),blk,0,stream>>>(qkvb, ob, lsb,
                                     x1o, f1_w,f1_b,f2_w,f2_b, t1,
                                     X, wgt, bc2, hq);
  k_s3 <<<dim3(576),blk,0,stream>>>(t1, g_w,g_b,bn_g, t2,
                                     X, ob, lsb, proj_w, bn_n4, xa,
                                     hq, hz_w, D_p, out_w, ho);
  k_s4 <<<dim3(768),blk,0,stream>>>(t2, dw2_w, dw2_b, xa, ho, bc2);
  k_mid<<<dim3(1024),blk,0,stream>>>(xa,mlp1_w,bn_mlp,mid);
  k_out<<<dim3(1024),blk,0,stream>>>(X,mid,mlp2_w,bn_n1,(float*)d_out);
}